// Round 13
// baseline (156.727 us; speedup 1.0000x reference)
//
#include <hip/hip_runtime.h>
#include <hip/hip_bf16.h>
#include <cstdint>
#include <cstddef>

constexpr int B_ = 2;
constexpr int HH = 192, WW = 192, HW_ = HH * WW;
constexpr int HP = 194, WPAD = 200;   // padded dims

typedef short bf16x8 __attribute__((ext_vector_type(8)));
typedef short s16x4  __attribute__((ext_vector_type(4)));
typedef float f32x4  __attribute__((ext_vector_type(4)));
typedef unsigned int u32x4 __attribute__((ext_vector_type(4)));

typedef __attribute__((address_space(1))) const void GLB;
typedef __attribute__((address_space(3))) void LDS;

__device__ __forceinline__ float bf2f(unsigned short h) {
  union { unsigned u; float f; } v; v.u = (unsigned)h << 16; return v.f;
}
__device__ __forceinline__ unsigned short f2bf(float f) {
  union { float f; unsigned u; } v; v.f = f;
  unsigned u = v.u;
  u += 0x7fffu + ((u >> 16) & 1u);
  return (unsigned short)(u >> 16);
}
__device__ __forceinline__ float leaky(float v) { return fmaxf(v, 0.1f * v); }

// ---------------------------------------------------------------------------
// prep0: fused (a) offsets NCHW->NHWC, (b) weight transforms, (c) border zero.
// Block-ranges: [0,4608) = to_nhwc, [4608,5508) = wxform, [5508,5812) = border.
// ---------------------------------------------------------------------------
__global__ __launch_bounds__(256) void prep0(
    const float* __restrict__ offin,
    const float* __restrict__ w_off, const float* __restrict__ w_dcn,
    const float* __restrict__ w_r1,  const float* __restrict__ w_r2,
    unsigned short* __restrict__ offs_t, unsigned short* __restrict__ concat_t,
    unsigned short* __restrict__ r1_t,
    unsigned short* __restrict__ wOffB, unsigned short* __restrict__ wDcnB,
    unsigned short* __restrict__ wR1B,  unsigned short* __restrict__ wR2B)
{
  __shared__ float tile[16][65];
  int bid = blockIdx.x;
  int t = threadIdx.x;

  if (bid < 4608) {
    // ---- offsets input: NCHW f32 -> padded NHWC bf16 (64 ch)
    int bx = bid % 12, by = bid / 12;
    int xc = bx * 16;
    int y = by % HH, b = by / HH;
    #pragma unroll
    for (int cp = 0; cp < 4; ++cp) {
      int c = cp * 16 + (t >> 4);
      tile[t & 15][c] = offin[((size_t)(b * 64 + c) * HH + y) * WW + xc + (t & 15)];
    }
    __syncthreads();
    int x = t >> 4, c4 = (t & 15) * 4;
    s16x4 s;
    #pragma unroll
    for (int j = 0; j < 4; ++j) s[j] = (short)f2bf(tile[x][c4 + j]);
    *(s16x4*)&offs_t[((size_t)(b * HP + y + 1) * WPAD + xc + x + 1) * 64 + c4] = s;
  } else if (bid < 5508) {
    // ---- weight transforms: (O,CI,3,3) f32 -> tap-major [k][o][ci] bf16
    int tid = (bid - 4608) * 256 + t;           // [0, 230400)
    const float* src; unsigned short* dst; int CI, CO, idx; bool dosw = true;
    if (tid < 82944)       { src = w_off; dst = wOffB; CI = 64;  CO = 144; idx = tid; }
    else if (tid < 119808) { src = w_dcn; dst = wDcnB; CI = 64;  CO = 64;  idx = tid - 82944; dosw = false; }
    else if (tid < 193536) { src = w_r1;  dst = wR1B;  CI = 128; CO = 64;  idx = tid - 119808; }
    else                   { src = w_r2;  dst = wR2B;  CI = 64;  CO = 64;  idx = tid - 193536; }
    int ci = idx % CI;
    int k  = (idx / CI) % 9;
    int o  = idx / (CI * 9);
    int pci = dosw ? (((((ci >> 3) ^ (o & 7))) << 3) | (ci & 7)) : ci;
    dst[((size_t)k * CO + o) * CI + pci] = f2bf(src[((size_t)o * CI + ci) * 9 + k]);
  } else {
    // ---- border zeroing of the three padded NHWC buffers
    int tid = (bid - 5508) * 256 + t;           // covers 77600
    if (tid >= B_ * HP * WPAD) return;
    int x = tid % WPAD, y = (tid / WPAD) % HP, b = tid / (HP * WPAD);
    bool border = (y == 0) || (y >= 193) || (x == 0) || (x >= 193);
    if (!border) return;
    size_t px = (size_t)(b * HP + y) * WPAD + x;
    u32x4 z4 = {0u, 0u, 0u, 0u};
    u32x4* p0 = (u32x4*)(offs_t   + px * 64);
    u32x4* p1 = (u32x4*)(concat_t + px * 128);
    u32x4* p2 = (u32x4*)(r1_t     + px * 64);
    #pragma unroll
    for (int i = 0; i < 8; ++i)  p0[i] = z4;
    #pragma unroll
    for (int i = 0; i < 16; ++i) p1[i] = z4;
    #pragma unroll
    for (int i = 0; i < 8; ++i)  p2[i] = z4;
  }
}

// ---------------------------------------------------------------------------
// prev NCHW f32 -> BOTH concat_t ch[64,128) (padded NHWC) AND group-planar gp.
// ---------------------------------------------------------------------------
__global__ __launch_bounds__(256) void prep_prev(const float* __restrict__ src,
                                                 unsigned short* __restrict__ concatT,
                                                 unsigned short* __restrict__ gp)
{
  __shared__ float tile[16][65];
  int t = threadIdx.x;
  int xc = blockIdx.x * 16;
  int y = blockIdx.y % HH, b = blockIdx.y / HH;
  #pragma unroll
  for (int cp = 0; cp < 4; ++cp) {
    int c = cp * 16 + (t >> 4);
    tile[t & 15][c] = src[((size_t)(b * 64 + c) * HH + y) * WW + xc + (t & 15)];
  }
  __syncthreads();
  int x = t >> 4, c4 = (t & 15) * 4;
  s16x4 s;
  #pragma unroll
  for (int j = 0; j < 4; ++j) s[j] = (short)f2bf(tile[x][c4 + j]);
  *(s16x4*)&concatT[((size_t)(b * HP + y + 1) * WPAD + xc + x + 1) * 128 + 64 + c4] = s;
  int g = c4 >> 3, co = c4 & 7;
  *(s16x4*)&gp[((size_t)(b * 8 + g) * HW_ + (size_t)y * WW + xc + x) * 8 + co] = s;
}

// ---------------------------------------------------------------------------
// MFMA implicit-GEMM 3x3 conv. Pixels staged once in LDS; per-tap weight
// SLICE (NF*16 couts at co0 = blockIdx.z*NF*16) staged via global_load_lds.
// All weight-staging trip counts are multiples of 128 (full waves only).
// OUTMODE 0: bf16 NCHW (K1) | 1: bf16 NHWC padded (K3) | 2: f32 NCHW + resid (K4)
// ---------------------------------------------------------------------------
template<int CIN, int COUT, int NF, bool LEAKY_, int OUTMODE, bool DBUF>
__global__ __launch_bounds__(256, 4) void conv_mfma(
    const unsigned short* __restrict__ inT,   // [b][HP][WPAD][CIN] bf16
    const unsigned short* __restrict__ wS,    // [9][COUT][CIN] bf16, swizzled image
    const float* __restrict__ bias,
    const unsigned short* __restrict__ resid,
    void* __restrict__ outp)
{
  constexpr int CPP  = CIN / 8;          // 16B chunks per pixel
  constexpr int TPX  = 72;
  constexpr int NCH  = TPX * CPP;        // chunks per staged row
  constexpr int RPR  = NCH / 64;         // wave-regions per row
  constexpr int NREG = 3 * RPR;
  constexpr int WSZ  = NF * 16 * CIN;    // weight elems per tap slice
  constexpr int WCH  = WSZ / 8;          // 16B chunks per tap slice
  static_assert(WCH % 128 == 0, "staging must use full waves");
  __shared__ __align__(16) unsigned short tile[3 * TPX * CIN];
  __shared__ __align__(16) unsigned short wlds[(DBUF ? 2 : 1) * WSZ];

  const int t = threadIdx.x;
  const int l = t & 63, wv = t >> 6;
  const int lr = l & 15, lq = l >> 4, lk = lq * 8;

  // XCD-aware bijective swizzle over the spatial grid (1152 % 8 == 0)
  constexpr int NWG = 3 * 384;
  int lin = blockIdx.x + 3 * blockIdx.y;
  int swz = (lin & 7) * (NWG / 8) + (lin >> 3);
  int xq = swz % 3, yy = swz / 3;
  int y = yy % HH, b = yy / HH;
  int x0 = xq * 64;
  const int co0 = blockIdx.z * (NF * 16);   // cout slice origin (mult of 32)

  // ---- stage 3 pixel rows (72 px each, swizzled) + weight tap-0 slice
  {
    const unsigned short* base = inT + ((size_t)(b * HP + y) * WPAD + x0) * CIN;
    for (int r = wv; r < NREG; r += 4) {
      int row = r / RPR;
      int rr  = r % RPR;
      int d   = rr * 64 + l;
      int p   = d / CPP;
      int cj  = d % CPP;
      int sc  = p * CPP + (cj ^ (p & (CPP - 1)));
      const unsigned short* src = base + (size_t)row * WPAD * CIN + (size_t)sc * 8;
      unsigned short* dst = &tile[(size_t)(row * NCH + rr * 64) * 8];
      __builtin_amdgcn_global_load_lds((GLB*)src, (LDS*)dst, 16, 0, 0);
    }
  }
  {
    const unsigned short* srcb = wS + (size_t)co0 * CIN;   // tap 0 slice
    for (int r = t; r < WCH; r += 256)
      __builtin_amdgcn_global_load_lds((GLB*)(srcb + (size_t)r * 8),
                                       (LDS*)(&wlds[(size_t)r * 8]), 16, 0, 0);
  }
  __syncthreads();

  f32x4 acc[NF];
  #pragma unroll
  for (int f = 0; f < NF; ++f) acc[f] = f32x4{0.f, 0.f, 0.f, 0.f};

  #pragma unroll
  for (int k = 0; k < 9; ++k) {
    const int ky = k / 3, kx = k % 3;
    if (DBUF && k < 8) {
      const unsigned short* srcb = wS + (size_t)(k + 1) * COUT * CIN + (size_t)co0 * CIN;
      unsigned short* db = &wlds[(size_t)((k + 1) & 1) * WSZ];
      for (int r = t; r < WCH; r += 256)
        __builtin_amdgcn_global_load_lds((GLB*)(srcb + (size_t)r * 8),
                                         (LDS*)(db + (size_t)r * 8), 16, 0, 0);
    }
    // ---- compute tap k
    {
      const unsigned short* wb = &wlds[DBUF ? (size_t)(k & 1) * WSZ : 0];
      const int px = wv * 16 + lr + kx;
      #pragma unroll
      for (int c = 0; c < CIN; c += 32) {
        int cj = (c + lk) >> 3;
        bf16x8 pf = *(const bf16x8*)
            &tile[(size_t)(ky * NCH + px * CPP + (cj ^ (px & (CPP - 1)))) * 8];
        #pragma unroll
        for (int f = 0; f < NF; ++f) {
          int co = f * 16 + lr;             // local row; (co0+co)&7 == co&7
          bf16x8 wf = *(const bf16x8*)&wb[(size_t)co * CIN + ((cj ^ (co & 7)) << 3)];
          if (OUTMODE == 0)
            acc[f] = __builtin_amdgcn_mfma_f32_16x16x32_bf16(pf, wf, acc[f], 0, 0, 0);
          else
            acc[f] = __builtin_amdgcn_mfma_f32_16x16x32_bf16(wf, pf, acc[f], 0, 0, 0);
        }
      }
    }
    if (DBUF) {
      __syncthreads();
    } else if (k < 8) {
      __syncthreads();                       // all reads of wlds done
      const unsigned short* srcb = wS + (size_t)(k + 1) * COUT * CIN + (size_t)co0 * CIN;
      for (int r = t; r < WCH; r += 256)
        __builtin_amdgcn_global_load_lds((GLB*)(srcb + (size_t)r * 8),
                                         (LDS*)(&wlds[(size_t)r * 8]), 16, 0, 0);
      __syncthreads();                       // staging complete
    }
  }

  if (OUTMODE == 0) {
    int xs = x0 + wv * 16 + lq * 4;
    #pragma unroll
    for (int f = 0; f < NF; ++f) {
      int coG = co0 + f * 16 + lr;
      float bv = bias[coG];
      s16x4 s;
      #pragma unroll
      for (int j = 0; j < 4; ++j) {
        float v = acc[f][j] + bv;
        if (LEAKY_) v = leaky(v);
        s[j] = (short)f2bf(v);
      }
      *(s16x4*)((unsigned short*)outp + ((size_t)(b * COUT + coG) * HH + y) * WW + xs) = s;
    }
  } else if (OUTMODE == 1) {
    int x = x0 + wv * 16 + lr;
    #pragma unroll
    for (int f = 0; f < NF; ++f) {
      int coG = co0 + f * 16 + lq * 4;
      f32x4 bv = *(const f32x4*)&bias[coG];
      s16x4 s;
      #pragma unroll
      for (int j = 0; j < 4; ++j) {
        float v = acc[f][j] + bv[j];
        if (LEAKY_) v = leaky(v);
        s[j] = (short)f2bf(v);
      }
      *(s16x4*)((unsigned short*)outp + ((size_t)(b * HP + y + 1) * WPAD + x + 1) * 64 + coG) = s;
    }
  } else {
    int x = x0 + wv * 16 + lr;
    const unsigned short* rbase = resid + ((size_t)(b * HP + y + 1) * WPAD + x + 1) * 128;
    float* ob = (float*)outp + (size_t)b * 64 * HW_ + (size_t)y * WW + x;
    #pragma unroll
    for (int f = 0; f < NF; ++f) {
      int cobG = co0 + f * 16 + lq * 4;
      f32x4 bv = *(const f32x4*)&bias[cobG];
      s16x4 rv = *(const s16x4*)&rbase[cobG];
      #pragma unroll
      for (int j = 0; j < 4; ++j) {
        float v = acc[f][j] + bv[j];
        if (LEAKY_) v = leaky(v);
        v += bf2f((unsigned short)rv[j]);
        ob[(size_t)(cobG + j) * HW_] = v;
      }
    }
  }
}

// ---------------------------------------------------------------------------
// Deformable conv (R11-proven: passes both validations). LDS-window, 2x32
// tile, 2048-slot full-wave staging, group stride 241 slots.
// ---------------------------------------------------------------------------
__global__ __launch_bounds__(256, 4) void deform_mfma(
    const unsigned short* __restrict__ gp,    // [b][8][192][192][8] bf16
    const unsigned short* __restrict__ off,   // [b][144][192][192] bf16
    const unsigned short* __restrict__ wD,    // [9][64][64] bf16 plain
    const float* __restrict__ bias,
    unsigned short* __restrict__ concatT)     // [b][HP][WPAD][128], writes ch0-63
{
  __shared__ __align__(16) unsigned short win[2048 * 8];   // 32768 B
  const int t = threadIdx.x;
  const int l = t & 63, wv = t >> 6;
  const int lr = l & 15, lq = l >> 4;

  int lin = blockIdx.x;                       // 1152 blocks
  int swz = (lin & 7) * 144 + (lin >> 3);     // XCD-aware bijective
  int xt = swz % 6;
  int rest = swz / 6;                         // 0..191
  int yp = rest % 96, b = rest / 96;
  int Y = yp * 2, x0 = xt * 32;
  int yrow = Y + (wv >> 1);                   // this wave's output row
  int xpix = x0 + (wv & 1) * 16 + lr;         // this lane's pixel

  const int wy = Y - 2, wx = x0 - 3;          // window origin (image coords)
  const unsigned short* gpb = gp + (size_t)b * 8 * HW_ * 8;

  // ---- stage window: 2048 slots x 16B, all waves FULLY ACTIVE each iter
  #pragma unroll
  for (int i = 0; i < 8; ++i) {
    int p  = t + i * 256;                     // 0..2047
    int g  = min(p / 241, 7);
    int rc = p - g * 241;
    int rcc = min(rc, 239);                   // pad slots -> clamped source
    int r  = rcc / 40;
    int c  = rcc - r * 40;
    int yr = min(max(wy + r, 0), HH - 1);
    int xc = min(max(wx + c, 0), WW - 1);
    const unsigned short* src = gpb + ((size_t)g * HW_ + (size_t)yr * WW + xc) * 8;
    __builtin_amdgcn_global_load_lds((GLB*)src,
                                     (LDS*)(win + (size_t)p * 8), 16, 0, 0);
  }

  // ---- preload offsets, packed (dy | dx<<16) per (group-pair, tap)
  unsigned dd[2][9];
  #pragma unroll
  for (int gi = 0; gi < 2; ++gi) {
    int g = lq + gi * 4;
    const unsigned short* op = off + ((size_t)(b * 144 + g * 18) * HH + yrow) * WW + xpix;
    #pragma unroll
    for (int k = 0; k < 9; ++k) {
      unsigned dyv = op[(size_t)(2 * k) * HW_];
      unsigned dxv = op[(size_t)(2 * k + 1) * HW_];
      dd[gi][k] = dyv | (dxv << 16);
    }
  }

  __syncthreads();                            // window ready (single barrier)

  f32x4 acc[4];
  #pragma unroll
  for (int f = 0; f < 4; ++f) acc[f] = f32x4{0.f, 0.f, 0.f, 0.f};

  #pragma unroll
  for (int k = 0; k < 9; ++k) {
    const int ky = k / 3, kx = k % 3;
    bf16x8 pf0, pf1;
    #pragma unroll
    for (int gi = 0; gi < 2; ++gi) {
      int g = lq + gi * 4;
      float dyv = bf2f((unsigned short)(dd[gi][k] & 0xffffu));
      float dxv = bf2f((unsigned short)(dd[gi][k] >> 16));
      float py = (float)(yrow - 1 + ky) + dyv;
      float px = (float)(xpix - 1 + kx) + dxv;
      float fy0 = floorf(py), fx0 = floorf(px);
      float wy1 = py - fy0, wx1 = px - fx0;
      float wy0 = 1.f - wy1, wx0 = 1.f - wx1;
      bool vy0 = (fy0 >= 0.f)  && (fy0 <= 191.f);
      bool vy1 = (fy0 >= -1.f) && (fy0 <= 190.f);
      bool vx0 = (fx0 >= 0.f)  && (fx0 <= 191.f);
      bool vx1 = (fx0 >= -1.f) && (fx0 <= 190.f);
      float c00 = (vy0 && vx0) ? wy0 * wx0 : 0.f;
      float c01 = (vy0 && vx1) ? wy0 * wx1 : 0.f;
      float c10 = (vy1 && vx0) ? wy1 * wx0 : 0.f;
      float c11 = (vy1 && vx1) ? wy1 * wx1 : 0.f;
      int iy0 = (int)fminf(fmaxf(fy0, 0.f), 191.f);
      int iy1 = (int)fminf(fmaxf(fy0 + 1.f, 0.f), 191.f);
      int ix0 = (int)fminf(fmaxf(fx0, 0.f), 191.f);
      int ix1 = (int)fminf(fmaxf(fx0 + 1.f, 0.f), 191.f);
      bool inw = (iy0 >= wy) && (iy1 <= wy + 5) && (ix0 >= wx) && (ix1 <= wx + 39);
      int ry0 = min(max(iy0 - wy, 0), 5), ry1 = min(max(iy1 - wy, 0), 5);
      int rx0 = min(max(ix0 - wx, 0), 39), rx1 = min(max(ix1 - wx, 0), 39);
      const unsigned short* wg = win + (size_t)g * (241 * 8);
      bf16x8 v00 = *(const bf16x8*)(wg + ((size_t)ry0 * 40 + rx0) * 8);
      bf16x8 v01 = *(const bf16x8*)(wg + ((size_t)ry0 * 40 + rx1) * 8);
      bf16x8 v10 = *(const bf16x8*)(wg + ((size_t)ry1 * 40 + rx0) * 8);
      bf16x8 v11 = *(const bf16x8*)(wg + ((size_t)ry1 * 40 + rx1) * 8);
      if (!__all((int)inw)) {                 // rare: exact global fallback
        if (!inw) {
          const unsigned short* bb = gpb + (size_t)g * HW_ * 8;
          v00 = *(const bf16x8*)(bb + ((size_t)iy0 * WW + ix0) * 8);
          v01 = *(const bf16x8*)(bb + ((size_t)iy0 * WW + ix1) * 8);
          v10 = *(const bf16x8*)(bb + ((size_t)iy1 * WW + ix0) * 8);
          v11 = *(const bf16x8*)(bb + ((size_t)iy1 * WW + ix1) * 8);
        }
      }
      bf16x8 sv;
      #pragma unroll
      for (int j = 0; j < 8; ++j) {
        float s = bf2f((unsigned short)v00[j]) * c00
                + bf2f((unsigned short)v01[j]) * c01
                + bf2f((unsigned short)v10[j]) * c10
                + bf2f((unsigned short)v11[j]) * c11;
        sv[j] = (short)f2bf(s);
      }
      if (gi == 0) pf0 = sv; else pf1 = sv;
    }
    #pragma unroll
    for (int f = 0; f < 4; ++f) {
      bf16x8 wf = *(const bf16x8*)&wD[((size_t)k * 64 + f * 16 + lr) * 64 + lq * 8];
      acc[f] = __builtin_amdgcn_mfma_f32_16x16x32_bf16(wf, pf0, acc[f], 0, 0, 0);
    }
    #pragma unroll
    for (int f = 0; f < 4; ++f) {
      bf16x8 wf = *(const bf16x8*)&wD[((size_t)k * 64 + f * 16 + lr) * 64 + 32 + lq * 8];
      acc[f] = __builtin_amdgcn_mfma_f32_16x16x32_bf16(wf, pf1, acc[f], 0, 0, 0);
    }
  }

  // epilogue: NHWC bf16 into concat channels [0,64)
  unsigned short* outc = concatT + (size_t)b * HP * WPAD * 128;
  #pragma unroll
  for (int f = 0; f < 4; ++f) {
    int co = f * 16 + lq * 4;
    f32x4 bv = *(const f32x4*)&bias[co];
    s16x4 s;
    #pragma unroll
    for (int j = 0; j < 4; ++j) s[j] = (short)f2bf(acc[f][j] + bv[j]);
    *(s16x4*)&outc[((size_t)(yrow + 1) * WPAD + xpix + 1) * 128 + co] = s;
  }
}

// ---------------------------------------------------------------------------
extern "C" void kernel_launch(void* const* d_in, const int* in_sizes, int n_in,
                              void* d_out, int out_size, void* d_ws, size_t ws_size,
                              hipStream_t stream)
{
  const float* prev  = (const float*)d_in[0];
  const float* offin = (const float*)d_in[1];
  const float* w_off = (const float*)d_in[2];
  const float* b_off = (const float*)d_in[3];
  const float* w_dcn = (const float*)d_in[4];
  const float* b_dcn = (const float*)d_in[5];
  const float* w_r1  = (const float*)d_in[6];
  const float* b_r1  = (const float*)d_in[7];
  const float* w_r2  = (const float*)d_in[8];
  const float* b_r2  = (const float*)d_in[9];
  float* out = (float*)d_out;

  char* p = (char*)d_ws;
  unsigned short* offs_t   = (unsigned short*)p; p += (size_t)B_ * HP * WPAD * 64 * 2;   //  9.93 MB
  unsigned short* concat_t = (unsigned short*)p; p += (size_t)B_ * HP * WPAD * 128 * 2;  // 19.87 MB
  unsigned short* r1_t     = (unsigned short*)p; p += (size_t)B_ * HP * WPAD * 64 * 2;   //  9.93 MB
  unsigned short* offf     = (unsigned short*)p; p += (size_t)B_ * 144 * HW_ * 2;        // 21.23 MB
  unsigned short* wOffB    = (unsigned short*)p; p += 144 * 576 * 2;
  unsigned short* wDcnB    = (unsigned short*)p; p += 64 * 576 * 2;
  unsigned short* wR1B     = (unsigned short*)p; p += 64 * 1152 * 2;
  unsigned short* wR2B     = (unsigned short*)p; p += 64 * 576 * 2;                      // total ~61.4 MB
  // gp aliases offs_t: offs_t is dead after K1; prep_prev runs after K1.
  unsigned short* gp = offs_t;

  // prep0: offsets->NHWC + weight transforms + border zeroing (fused)
  prep0<<<5812, 256, 0, stream>>>(offin, w_off, w_dcn, w_r1, w_r2,
                                  offs_t, concat_t, r1_t,
                                  wOffB, wDcnB, wR1B, wR2B);

  // K1: offset conv (64 -> 144), cout-split x3 (grid 3456).
  conv_mfma<64, 144, 3, false, 0, true><<<dim3(3, 384, 3), 256, 0, stream>>>(
      offs_t, wOffB, b_off, nullptr, offf);

  // prev -> concat ch[64,128) + group-planar gp (fused; overwrites offs_t)
  prep_prev<<<dim3(12, 384), 256, 0, stream>>>(prev, concat_t, gp);

  // K2: deformable conv -> concat_t channels [0,64).
  deform_mfma<<<1152, 256, 0, stream>>>(gp, offf, wDcnB, b_dcn, concat_t);

  // K3: r1 = leaky(conv(concat)) (128 -> 64), cout-split x2, DBUF.
  conv_mfma<128, 64, 2, true, 1, true><<<dim3(3, 384, 2), 256, 0, stream>>>(
      concat_t, wR1B, b_r1, nullptr, r1_t);

  // K4: out = aligned + leaky(conv(r1)) (64 -> 64), cout-split x2, DBUF.
  conv_mfma<64, 64, 2, true, 2, true><<<dim3(3, 384, 2), 256, 0, stream>>>(
      r1_t, wR2B, b_r2, concat_t, out);
}

// Round 14
// 147.964 us; speedup vs baseline: 1.0592x; 1.0592x over previous
//
#include <hip/hip_runtime.h>
#include <hip/hip_bf16.h>
#include <cstdint>
#include <cstddef>

constexpr int B_ = 2;
constexpr int HH = 192, WW = 192, HW_ = HH * WW;
constexpr int HP = 194, WPAD = 200;   // padded dims

typedef short bf16x8 __attribute__((ext_vector_type(8)));
typedef short s16x4  __attribute__((ext_vector_type(4)));
typedef float f32x4  __attribute__((ext_vector_type(4)));
typedef unsigned int u32x4 __attribute__((ext_vector_type(4)));

typedef __attribute__((address_space(1))) const void GLB;
typedef __attribute__((address_space(3))) void LDS;

__device__ __forceinline__ float bf2f(unsigned short h) {
  union { unsigned u; float f; } v; v.u = (unsigned)h << 16; return v.f;
}
__device__ __forceinline__ unsigned short f2bf(float f) {
  union { float f; unsigned u; } v; v.f = f;
  unsigned u = v.u;
  u += 0x7fffu + ((u >> 16) & 1u);
  return (unsigned short)(u >> 16);
}
__device__ __forceinline__ float leaky(float v) { return fmaxf(v, 0.1f * v); }

// ---------------------------------------------------------------------------
// prep0: fused (a) offsets NCHW->NHWC, (b) weight transforms, (c) border zero.
// Block-ranges: [0,4608) = to_nhwc, [4608,5508) = wxform, [5508,5812) = border.
// ---------------------------------------------------------------------------
__global__ __launch_bounds__(256) void prep0(
    const float* __restrict__ offin,
    const float* __restrict__ w_off, const float* __restrict__ w_dcn,
    const float* __restrict__ w_r1,  const float* __restrict__ w_r2,
    unsigned short* __restrict__ offs_t, unsigned short* __restrict__ concat_t,
    unsigned short* __restrict__ r1_t,
    unsigned short* __restrict__ wOffB, unsigned short* __restrict__ wDcnB,
    unsigned short* __restrict__ wR1B,  unsigned short* __restrict__ wR2B)
{
  __shared__ float tile[16][65];
  int bid = blockIdx.x;
  int t = threadIdx.x;

  if (bid < 4608) {
    // ---- offsets input: NCHW f32 -> padded NHWC bf16 (64 ch)
    int bx = bid % 12, by = bid / 12;
    int xc = bx * 16;
    int y = by % HH, b = by / HH;
    #pragma unroll
    for (int cp = 0; cp < 4; ++cp) {
      int c = cp * 16 + (t >> 4);
      tile[t & 15][c] = offin[((size_t)(b * 64 + c) * HH + y) * WW + xc + (t & 15)];
    }
    __syncthreads();
    int x = t >> 4, c4 = (t & 15) * 4;
    s16x4 s;
    #pragma unroll
    for (int j = 0; j < 4; ++j) s[j] = (short)f2bf(tile[x][c4 + j]);
    *(s16x4*)&offs_t[((size_t)(b * HP + y + 1) * WPAD + xc + x + 1) * 64 + c4] = s;
  } else if (bid < 5508) {
    // ---- weight transforms: (O,CI,3,3) f32 -> tap-major [k][o][ci] bf16
    int tid = (bid - 4608) * 256 + t;           // [0, 230400)
    const float* src; unsigned short* dst; int CI, CO, idx; bool dosw = true;
    if (tid < 82944)       { src = w_off; dst = wOffB; CI = 64;  CO = 144; idx = tid; }
    else if (tid < 119808) { src = w_dcn; dst = wDcnB; CI = 64;  CO = 64;  idx = tid - 82944; dosw = false; }
    else if (tid < 193536) { src = w_r1;  dst = wR1B;  CI = 128; CO = 64;  idx = tid - 119808; }
    else                   { src = w_r2;  dst = wR2B;  CI = 64;  CO = 64;  idx = tid - 193536; }
    int ci = idx % CI;
    int k  = (idx / CI) % 9;
    int o  = idx / (CI * 9);
    int pci = dosw ? (((((ci >> 3) ^ (o & 7))) << 3) | (ci & 7)) : ci;
    dst[((size_t)k * CO + o) * CI + pci] = f2bf(src[((size_t)o * CI + ci) * 9 + k]);
  } else {
    // ---- border zeroing of the three padded NHWC buffers
    int tid = (bid - 5508) * 256 + t;           // covers 77600
    if (tid >= B_ * HP * WPAD) return;
    int x = tid % WPAD, y = (tid / WPAD) % HP, b = tid / (HP * WPAD);
    bool border = (y == 0) || (y >= 193) || (x == 0) || (x >= 193);
    if (!border) return;
    size_t px = (size_t)(b * HP + y) * WPAD + x;
    u32x4 z4 = {0u, 0u, 0u, 0u};
    u32x4* p0 = (u32x4*)(offs_t   + px * 64);
    u32x4* p1 = (u32x4*)(concat_t + px * 128);
    u32x4* p2 = (u32x4*)(r1_t     + px * 64);
    #pragma unroll
    for (int i = 0; i < 8; ++i)  p0[i] = z4;
    #pragma unroll
    for (int i = 0; i < 16; ++i) p1[i] = z4;
    #pragma unroll
    for (int i = 0; i < 8; ++i)  p2[i] = z4;
  }
}

// ---------------------------------------------------------------------------
// prev NCHW f32 -> BOTH concat_t ch[64,128) (padded NHWC) AND group-planar gp.
// ---------------------------------------------------------------------------
__global__ __launch_bounds__(256) void prep_prev(const float* __restrict__ src,
                                                 unsigned short* __restrict__ concatT,
                                                 unsigned short* __restrict__ gp)
{
  __shared__ float tile[16][65];
  int t = threadIdx.x;
  int xc = blockIdx.x * 16;
  int y = blockIdx.y % HH, b = blockIdx.y / HH;
  #pragma unroll
  for (int cp = 0; cp < 4; ++cp) {
    int c = cp * 16 + (t >> 4);
    tile[t & 15][c] = src[((size_t)(b * 64 + c) * HH + y) * WW + xc + (t & 15)];
  }
  __syncthreads();
  int x = t >> 4, c4 = (t & 15) * 4;
  s16x4 s;
  #pragma unroll
  for (int j = 0; j < 4; ++j) s[j] = (short)f2bf(tile[x][c4 + j]);
  *(s16x4*)&concatT[((size_t)(b * HP + y + 1) * WPAD + xc + x + 1) * 128 + 64 + c4] = s;
  int g = c4 >> 3, co = c4 & 7;
  *(s16x4*)&gp[((size_t)(b * 8 + g) * HW_ + (size_t)y * WW + xc + x) * 8 + co] = s;
}

// ---------------------------------------------------------------------------
// MFMA implicit-GEMM 3x3 conv. Pixels staged once in LDS; per-tap weight
// SLICE (NF*16 couts at co0 = blockIdx.z*NF*16) staged via global_load_lds.
// All weight-staging trip counts are multiples of 128 (full waves only).
// OUTMODE 0: bf16 NCHW (K1) | 1: bf16 NHWC padded (K3) | 2: f32 NCHW + resid (K4)
// R14: K3/K4 reverted to z=1 full-cout blocks (R12-proven — cout-split only
// pays when weights dominate staging, i.e. K1; for K3/K4 pixels dominate).
// ---------------------------------------------------------------------------
template<int CIN, int COUT, int NF, bool LEAKY_, int OUTMODE, bool DBUF>
__global__ __launch_bounds__(256, 4) void conv_mfma(
    const unsigned short* __restrict__ inT,   // [b][HP][WPAD][CIN] bf16
    const unsigned short* __restrict__ wS,    // [9][COUT][CIN] bf16, swizzled image
    const float* __restrict__ bias,
    const unsigned short* __restrict__ resid,
    void* __restrict__ outp)
{
  constexpr int CPP  = CIN / 8;          // 16B chunks per pixel
  constexpr int TPX  = 72;
  constexpr int NCH  = TPX * CPP;        // chunks per staged row
  constexpr int RPR  = NCH / 64;         // wave-regions per row
  constexpr int NREG = 3 * RPR;
  constexpr int WSZ  = NF * 16 * CIN;    // weight elems per tap slice
  constexpr int WCH  = WSZ / 8;          // 16B chunks per tap slice
  static_assert(WCH % 128 == 0, "staging must use full waves");
  __shared__ __align__(16) unsigned short tile[3 * TPX * CIN];
  __shared__ __align__(16) unsigned short wlds[(DBUF ? 2 : 1) * WSZ];

  const int t = threadIdx.x;
  const int l = t & 63, wv = t >> 6;
  const int lr = l & 15, lq = l >> 4, lk = lq * 8;

  // XCD-aware bijective swizzle over the spatial grid (1152 % 8 == 0)
  constexpr int NWG = 3 * 384;
  int lin = blockIdx.x + 3 * blockIdx.y;
  int swz = (lin & 7) * (NWG / 8) + (lin >> 3);
  int xq = swz % 3, yy = swz / 3;
  int y = yy % HH, b = yy / HH;
  int x0 = xq * 64;
  const int co0 = blockIdx.z * (NF * 16);   // cout slice origin (mult of 16)

  // ---- stage 3 pixel rows (72 px each, swizzled) + weight tap-0 slice
  {
    const unsigned short* base = inT + ((size_t)(b * HP + y) * WPAD + x0) * CIN;
    for (int r = wv; r < NREG; r += 4) {
      int row = r / RPR;
      int rr  = r % RPR;
      int d   = rr * 64 + l;
      int p   = d / CPP;
      int cj  = d % CPP;
      int sc  = p * CPP + (cj ^ (p & (CPP - 1)));
      const unsigned short* src = base + (size_t)row * WPAD * CIN + (size_t)sc * 8;
      unsigned short* dst = &tile[(size_t)(row * NCH + rr * 64) * 8];
      __builtin_amdgcn_global_load_lds((GLB*)src, (LDS*)dst, 16, 0, 0);
    }
  }
  {
    const unsigned short* srcb = wS + (size_t)co0 * CIN;   // tap 0 slice
    for (int r = t; r < WCH; r += 256)
      __builtin_amdgcn_global_load_lds((GLB*)(srcb + (size_t)r * 8),
                                       (LDS*)(&wlds[(size_t)r * 8]), 16, 0, 0);
  }
  __syncthreads();

  f32x4 acc[NF];
  #pragma unroll
  for (int f = 0; f < NF; ++f) acc[f] = f32x4{0.f, 0.f, 0.f, 0.f};

  #pragma unroll
  for (int k = 0; k < 9; ++k) {
    const int ky = k / 3, kx = k % 3;
    if (DBUF && k < 8) {
      const unsigned short* srcb = wS + (size_t)(k + 1) * COUT * CIN + (size_t)co0 * CIN;
      unsigned short* db = &wlds[(size_t)((k + 1) & 1) * WSZ];
      for (int r = t; r < WCH; r += 256)
        __builtin_amdgcn_global_load_lds((GLB*)(srcb + (size_t)r * 8),
                                         (LDS*)(db + (size_t)r * 8), 16, 0, 0);
    }
    // ---- compute tap k
    {
      const unsigned short* wb = &wlds[DBUF ? (size_t)(k & 1) * WSZ : 0];
      const int px = wv * 16 + lr + kx;
      #pragma unroll
      for (int c = 0; c < CIN; c += 32) {
        int cj = (c + lk) >> 3;
        bf16x8 pf = *(const bf16x8*)
            &tile[(size_t)(ky * NCH + px * CPP + (cj ^ (px & (CPP - 1)))) * 8];
        #pragma unroll
        for (int f = 0; f < NF; ++f) {
          int co = f * 16 + lr;             // local row; (co0+co)&7 == co&7
          bf16x8 wf = *(const bf16x8*)&wb[(size_t)co * CIN + ((cj ^ (co & 7)) << 3)];
          if (OUTMODE == 0)
            acc[f] = __builtin_amdgcn_mfma_f32_16x16x32_bf16(pf, wf, acc[f], 0, 0, 0);
          else
            acc[f] = __builtin_amdgcn_mfma_f32_16x16x32_bf16(wf, pf, acc[f], 0, 0, 0);
        }
      }
    }
    if (DBUF) {
      __syncthreads();
    } else if (k < 8) {
      __syncthreads();                       // all reads of wlds done
      const unsigned short* srcb = wS + (size_t)(k + 1) * COUT * CIN + (size_t)co0 * CIN;
      for (int r = t; r < WCH; r += 256)
        __builtin_amdgcn_global_load_lds((GLB*)(srcb + (size_t)r * 8),
                                         (LDS*)(&wlds[(size_t)r * 8]), 16, 0, 0);
      __syncthreads();                       // staging complete
    }
  }

  if (OUTMODE == 0) {
    int xs = x0 + wv * 16 + lq * 4;
    #pragma unroll
    for (int f = 0; f < NF; ++f) {
      int coG = co0 + f * 16 + lr;
      float bv = bias[coG];
      s16x4 s;
      #pragma unroll
      for (int j = 0; j < 4; ++j) {
        float v = acc[f][j] + bv;
        if (LEAKY_) v = leaky(v);
        s[j] = (short)f2bf(v);
      }
      *(s16x4*)((unsigned short*)outp + ((size_t)(b * COUT + coG) * HH + y) * WW + xs) = s;
    }
  } else if (OUTMODE == 1) {
    int x = x0 + wv * 16 + lr;
    #pragma unroll
    for (int f = 0; f < NF; ++f) {
      int coG = co0 + f * 16 + lq * 4;
      f32x4 bv = *(const f32x4*)&bias[coG];
      s16x4 s;
      #pragma unroll
      for (int j = 0; j < 4; ++j) {
        float v = acc[f][j] + bv[j];
        if (LEAKY_) v = leaky(v);
        s[j] = (short)f2bf(v);
      }
      *(s16x4*)((unsigned short*)outp + ((size_t)(b * HP + y + 1) * WPAD + x + 1) * 64 + coG) = s;
    }
  } else {
    int x = x0 + wv * 16 + lr;
    const unsigned short* rbase = resid + ((size_t)(b * HP + y + 1) * WPAD + x + 1) * 128;
    float* ob = (float*)outp + (size_t)b * 64 * HW_ + (size_t)y * WW + x;
    #pragma unroll
    for (int f = 0; f < NF; ++f) {
      int cobG = co0 + f * 16 + lq * 4;
      f32x4 bv = *(const f32x4*)&bias[cobG];
      s16x4 rv = *(const s16x4*)&rbase[cobG];
      #pragma unroll
      for (int j = 0; j < 4; ++j) {
        float v = acc[f][j] + bv[j];
        if (LEAKY_) v = leaky(v);
        v += bf2f((unsigned short)rv[j]);
        ob[(size_t)(cobG + j) * HW_] = v;
      }
    }
  }
}

// ---------------------------------------------------------------------------
// Deformable conv (R11-proven: passes both validations). LDS-window, 2x32
// tile, 2048-slot full-wave staging, group stride 241 slots.
// ---------------------------------------------------------------------------
__global__ __launch_bounds__(256, 4) void deform_mfma(
    const unsigned short* __restrict__ gp,    // [b][8][192][192][8] bf16
    const unsigned short* __restrict__ off,   // [b][144][192][192] bf16
    const unsigned short* __restrict__ wD,    // [9][64][64] bf16 plain
    const float* __restrict__ bias,
    unsigned short* __restrict__ concatT)     // [b][HP][WPAD][128], writes ch0-63
{
  __shared__ __align__(16) unsigned short win[2048 * 8];   // 32768 B
  const int t = threadIdx.x;
  const int l = t & 63, wv = t >> 6;
  const int lr = l & 15, lq = l >> 4;

  int lin = blockIdx.x;                       // 1152 blocks
  int swz = (lin & 7) * 144 + (lin >> 3);     // XCD-aware bijective
  int xt = swz % 6;
  int rest = swz / 6;                         // 0..191
  int yp = rest % 96, b = rest / 96;
  int Y = yp * 2, x0 = xt * 32;
  int yrow = Y + (wv >> 1);                   // this wave's output row
  int xpix = x0 + (wv & 1) * 16 + lr;         // this lane's pixel

  const int wy = Y - 2, wx = x0 - 3;          // window origin (image coords)
  const unsigned short* gpb = gp + (size_t)b * 8 * HW_ * 8;

  // ---- stage window: 2048 slots x 16B, all waves FULLY ACTIVE each iter
  #pragma unroll
  for (int i = 0; i < 8; ++i) {
    int p  = t + i * 256;                     // 0..2047
    int g  = min(p / 241, 7);
    int rc = p - g * 241;
    int rcc = min(rc, 239);                   // pad slots -> clamped source
    int r  = rcc / 40;
    int c  = rcc - r * 40;
    int yr = min(max(wy + r, 0), HH - 1);
    int xc = min(max(wx + c, 0), WW - 1);
    const unsigned short* src = gpb + ((size_t)g * HW_ + (size_t)yr * WW + xc) * 8;
    __builtin_amdgcn_global_load_lds((GLB*)src,
                                     (LDS*)(win + (size_t)p * 8), 16, 0, 0);
  }

  // ---- preload offsets, packed (dy | dx<<16) per (group-pair, tap)
  unsigned dd[2][9];
  #pragma unroll
  for (int gi = 0; gi < 2; ++gi) {
    int g = lq + gi * 4;
    const unsigned short* op = off + ((size_t)(b * 144 + g * 18) * HH + yrow) * WW + xpix;
    #pragma unroll
    for (int k = 0; k < 9; ++k) {
      unsigned dyv = op[(size_t)(2 * k) * HW_];
      unsigned dxv = op[(size_t)(2 * k + 1) * HW_];
      dd[gi][k] = dyv | (dxv << 16);
    }
  }

  __syncthreads();                            // window ready (single barrier)

  f32x4 acc[4];
  #pragma unroll
  for (int f = 0; f < 4; ++f) acc[f] = f32x4{0.f, 0.f, 0.f, 0.f};

  #pragma unroll
  for (int k = 0; k < 9; ++k) {
    const int ky = k / 3, kx = k % 3;
    bf16x8 pf0, pf1;
    #pragma unroll
    for (int gi = 0; gi < 2; ++gi) {
      int g = lq + gi * 4;
      float dyv = bf2f((unsigned short)(dd[gi][k] & 0xffffu));
      float dxv = bf2f((unsigned short)(dd[gi][k] >> 16));
      float py = (float)(yrow - 1 + ky) + dyv;
      float px = (float)(xpix - 1 + kx) + dxv;
      float fy0 = floorf(py), fx0 = floorf(px);
      float wy1 = py - fy0, wx1 = px - fx0;
      float wy0 = 1.f - wy1, wx0 = 1.f - wx1;
      bool vy0 = (fy0 >= 0.f)  && (fy0 <= 191.f);
      bool vy1 = (fy0 >= -1.f) && (fy0 <= 190.f);
      bool vx0 = (fx0 >= 0.f)  && (fx0 <= 191.f);
      bool vx1 = (fx0 >= -1.f) && (fx0 <= 190.f);
      float c00 = (vy0 && vx0) ? wy0 * wx0 : 0.f;
      float c01 = (vy0 && vx1) ? wy0 * wx1 : 0.f;
      float c10 = (vy1 && vx0) ? wy1 * wx0 : 0.f;
      float c11 = (vy1 && vx1) ? wy1 * wx1 : 0.f;
      int iy0 = (int)fminf(fmaxf(fy0, 0.f), 191.f);
      int iy1 = (int)fminf(fmaxf(fy0 + 1.f, 0.f), 191.f);
      int ix0 = (int)fminf(fmaxf(fx0, 0.f), 191.f);
      int ix1 = (int)fminf(fmaxf(fx0 + 1.f, 0.f), 191.f);
      bool inw = (iy0 >= wy) && (iy1 <= wy + 5) && (ix0 >= wx) && (ix1 <= wx + 39);
      int ry0 = min(max(iy0 - wy, 0), 5), ry1 = min(max(iy1 - wy, 0), 5);
      int rx0 = min(max(ix0 - wx, 0), 39), rx1 = min(max(ix1 - wx, 0), 39);
      const unsigned short* wg = win + (size_t)g * (241 * 8);
      bf16x8 v00 = *(const bf16x8*)(wg + ((size_t)ry0 * 40 + rx0) * 8);
      bf16x8 v01 = *(const bf16x8*)(wg + ((size_t)ry0 * 40 + rx1) * 8);
      bf16x8 v10 = *(const bf16x8*)(wg + ((size_t)ry1 * 40 + rx0) * 8);
      bf16x8 v11 = *(const bf16x8*)(wg + ((size_t)ry1 * 40 + rx1) * 8);
      if (!__all((int)inw)) {                 // rare: exact global fallback
        if (!inw) {
          const unsigned short* bb = gpb + (size_t)g * HW_ * 8;
          v00 = *(const bf16x8*)(bb + ((size_t)iy0 * WW + ix0) * 8);
          v01 = *(const bf16x8*)(bb + ((size_t)iy0 * WW + ix1) * 8);
          v10 = *(const bf16x8*)(bb + ((size_t)iy1 * WW + ix0) * 8);
          v11 = *(const bf16x8*)(bb + ((size_t)iy1 * WW + ix1) * 8);
        }
      }
      bf16x8 sv;
      #pragma unroll
      for (int j = 0; j < 8; ++j) {
        float s = bf2f((unsigned short)v00[j]) * c00
                + bf2f((unsigned short)v01[j]) * c01
                + bf2f((unsigned short)v10[j]) * c10
                + bf2f((unsigned short)v11[j]) * c11;
        sv[j] = (short)f2bf(s);
      }
      if (gi == 0) pf0 = sv; else pf1 = sv;
    }
    #pragma unroll
    for (int f = 0; f < 4; ++f) {
      bf16x8 wf = *(const bf16x8*)&wD[((size_t)k * 64 + f * 16 + lr) * 64 + lq * 8];
      acc[f] = __builtin_amdgcn_mfma_f32_16x16x32_bf16(wf, pf0, acc[f], 0, 0, 0);
    }
    #pragma unroll
    for (int f = 0; f < 4; ++f) {
      bf16x8 wf = *(const bf16x8*)&wD[((size_t)k * 64 + f * 16 + lr) * 64 + 32 + lq * 8];
      acc[f] = __builtin_amdgcn_mfma_f32_16x16x32_bf16(wf, pf1, acc[f], 0, 0, 0);
    }
  }

  // epilogue: NHWC bf16 into concat channels [0,64)
  unsigned short* outc = concatT + (size_t)b * HP * WPAD * 128;
  #pragma unroll
  for (int f = 0; f < 4; ++f) {
    int co = f * 16 + lq * 4;
    f32x4 bv = *(const f32x4*)&bias[co];
    s16x4 s;
    #pragma unroll
    for (int j = 0; j < 4; ++j) s[j] = (short)f2bf(acc[f][j] + bv[j]);
    *(s16x4*)&outc[((size_t)(yrow + 1) * WPAD + xpix + 1) * 128 + co] = s;
  }
}

// ---------------------------------------------------------------------------
extern "C" void kernel_launch(void* const* d_in, const int* in_sizes, int n_in,
                              void* d_out, int out_size, void* d_ws, size_t ws_size,
                              hipStream_t stream)
{
  const float* prev  = (const float*)d_in[0];
  const float* offin = (const float*)d_in[1];
  const float* w_off = (const float*)d_in[2];
  const float* b_off = (const float*)d_in[3];
  const float* w_dcn = (const float*)d_in[4];
  const float* b_dcn = (const float*)d_in[5];
  const float* w_r1  = (const float*)d_in[6];
  const float* b_r1  = (const float*)d_in[7];
  const float* w_r2  = (const float*)d_in[8];
  const float* b_r2  = (const float*)d_in[9];
  float* out = (float*)d_out;

  char* p = (char*)d_ws;
  unsigned short* offs_t   = (unsigned short*)p; p += (size_t)B_ * HP * WPAD * 64 * 2;   //  9.93 MB
  unsigned short* concat_t = (unsigned short*)p; p += (size_t)B_ * HP * WPAD * 128 * 2;  // 19.87 MB
  unsigned short* r1_t     = (unsigned short*)p; p += (size_t)B_ * HP * WPAD * 64 * 2;   //  9.93 MB
  unsigned short* offf     = (unsigned short*)p; p += (size_t)B_ * 144 * HW_ * 2;        // 21.23 MB
  unsigned short* wOffB    = (unsigned short*)p; p += 144 * 576 * 2;
  unsigned short* wDcnB    = (unsigned short*)p; p += 64 * 576 * 2;
  unsigned short* wR1B     = (unsigned short*)p; p += 64 * 1152 * 2;
  unsigned short* wR2B     = (unsigned short*)p; p += 64 * 576 * 2;                      // total ~61.4 MB
  // gp aliases offs_t: offs_t is dead after K1; prep_prev runs after K1.
  unsigned short* gp = offs_t;

  // prep0: offsets->NHWC + weight transforms + border zeroing (fused)
  prep0<<<5812, 256, 0, stream>>>(offin, w_off, w_dcn, w_r1, w_r2,
                                  offs_t, concat_t, r1_t,
                                  wOffB, wDcnB, wR1B, wR2B);

  // K1: offset conv (64 -> 144), cout-split x3 (grid 3456) — R12-proven.
  conv_mfma<64, 144, 3, false, 0, true><<<dim3(3, 384, 3), 256, 0, stream>>>(
      offs_t, wOffB, b_off, nullptr, offf);

  // prev -> concat ch[64,128) + group-planar gp (fused; overwrites offs_t)
  prep_prev<<<dim3(12, 384), 256, 0, stream>>>(prev, concat_t, gp);

  // K2: deformable conv -> concat_t channels [0,64).
  deform_mfma<<<1152, 256, 0, stream>>>(gp, offf, wDcnB, b_dcn, concat_t);

  // K3: r1 = leaky(conv(concat)) (128 -> 64), full cout, single-buf (R12).
  conv_mfma<128, 64, 4, true, 1, false><<<dim3(3, 384, 1), 256, 0, stream>>>(
      concat_t, wR1B, b_r1, nullptr, r1_t);

  // K4: out = aligned + leaky(conv(r1)) (64 -> 64), full cout, DBUF (R12).
  conv_mfma<64, 64, 4, true, 2, true><<<dim3(3, 384, 1), 256, 0, stream>>>(
      r1_t, wR2B, b_r2, concat_t, out);
}

// Round 15
// 144.965 us; speedup vs baseline: 1.0811x; 1.0207x over previous
//
#include <hip/hip_runtime.h>
#include <hip/hip_bf16.h>
#include <cstdint>
#include <cstddef>

constexpr int B_ = 2;
constexpr int HH = 192, WW = 192, HW_ = HH * WW;
constexpr int HP = 194, WPAD = 200;   // padded dims

typedef short bf16x8 __attribute__((ext_vector_type(8)));
typedef short s16x4  __attribute__((ext_vector_type(4)));
typedef float f32x4  __attribute__((ext_vector_type(4)));
typedef unsigned int u32x4 __attribute__((ext_vector_type(4)));

typedef __attribute__((address_space(1))) const void GLB;
typedef __attribute__((address_space(3))) void LDS;

__device__ __forceinline__ float bf2f(unsigned short h) {
  union { unsigned u; float f; } v; v.u = (unsigned)h << 16; return v.f;
}
__device__ __forceinline__ unsigned short f2bf(float f) {
  union { float f; unsigned u; } v; v.f = f;
  unsigned u = v.u;
  u += 0x7fffu + ((u >> 16) & 1u);
  return (unsigned short)(u >> 16);
}
__device__ __forceinline__ float leaky(float v) { return fmaxf(v, 0.1f * v); }

// ---------------------------------------------------------------------------
// prep0: fused (a) offsets NCHW->NHWC, (b) weight transforms, (c) border zero.
// Block-ranges: [0,4608) = to_nhwc, [4608,5508) = wxform, [5508,5812) = border.
// ---------------------------------------------------------------------------
__global__ __launch_bounds__(256) void prep0(
    const float* __restrict__ offin,
    const float* __restrict__ w_off, const float* __restrict__ w_dcn,
    const float* __restrict__ w_r1,  const float* __restrict__ w_r2,
    unsigned short* __restrict__ offs_t, unsigned short* __restrict__ concat_t,
    unsigned short* __restrict__ r1_t,
    unsigned short* __restrict__ wOffB, unsigned short* __restrict__ wDcnB,
    unsigned short* __restrict__ wR1B,  unsigned short* __restrict__ wR2B)
{
  __shared__ float tile[16][65];
  int bid = blockIdx.x;
  int t = threadIdx.x;

  if (bid < 4608) {
    // ---- offsets input: NCHW f32 -> padded NHWC bf16 (64 ch)
    int bx = bid % 12, by = bid / 12;
    int xc = bx * 16;
    int y = by % HH, b = by / HH;
    #pragma unroll
    for (int cp = 0; cp < 4; ++cp) {
      int c = cp * 16 + (t >> 4);
      tile[t & 15][c] = offin[((size_t)(b * 64 + c) * HH + y) * WW + xc + (t & 15)];
    }
    __syncthreads();
    int x = t >> 4, c4 = (t & 15) * 4;
    s16x4 s;
    #pragma unroll
    for (int j = 0; j < 4; ++j) s[j] = (short)f2bf(tile[x][c4 + j]);
    *(s16x4*)&offs_t[((size_t)(b * HP + y + 1) * WPAD + xc + x + 1) * 64 + c4] = s;
  } else if (bid < 5508) {
    // ---- weight transforms: (O,CI,3,3) f32 -> tap-major [k][o][ci] bf16
    int tid = (bid - 4608) * 256 + t;           // [0, 230400)
    const float* src; unsigned short* dst; int CI, CO, idx; bool dosw = true;
    if (tid < 82944)       { src = w_off; dst = wOffB; CI = 64;  CO = 144; idx = tid; }
    else if (tid < 119808) { src = w_dcn; dst = wDcnB; CI = 64;  CO = 64;  idx = tid - 82944; dosw = false; }
    else if (tid < 193536) { src = w_r1;  dst = wR1B;  CI = 128; CO = 64;  idx = tid - 119808; }
    else                   { src = w_r2;  dst = wR2B;  CI = 64;  CO = 64;  idx = tid - 193536; }
    int ci = idx % CI;
    int k  = (idx / CI) % 9;
    int o  = idx / (CI * 9);
    int pci = dosw ? (((((ci >> 3) ^ (o & 7))) << 3) | (ci & 7)) : ci;
    dst[((size_t)k * CO + o) * CI + pci] = f2bf(src[((size_t)o * CI + ci) * 9 + k]);
  } else {
    // ---- border zeroing of the three padded NHWC buffers
    int tid = (bid - 5508) * 256 + t;           // covers 77600
    if (tid >= B_ * HP * WPAD) return;
    int x = tid % WPAD, y = (tid / WPAD) % HP, b = tid / (HP * WPAD);
    bool border = (y == 0) || (y >= 193) || (x == 0) || (x >= 193);
    if (!border) return;
    size_t px = (size_t)(b * HP + y) * WPAD + x;
    u32x4 z4 = {0u, 0u, 0u, 0u};
    u32x4* p0 = (u32x4*)(offs_t   + px * 64);
    u32x4* p1 = (u32x4*)(concat_t + px * 128);
    u32x4* p2 = (u32x4*)(r1_t     + px * 64);
    #pragma unroll
    for (int i = 0; i < 8; ++i)  p0[i] = z4;
    #pragma unroll
    for (int i = 0; i < 16; ++i) p1[i] = z4;
    #pragma unroll
    for (int i = 0; i < 8; ++i)  p2[i] = z4;
  }
}

// ---------------------------------------------------------------------------
// prev NCHW f32 -> BOTH concat_t ch[64,128) (padded NHWC) AND group-planar gp.
// ---------------------------------------------------------------------------
__global__ __launch_bounds__(256) void prep_prev(const float* __restrict__ src,
                                                 unsigned short* __restrict__ concatT,
                                                 unsigned short* __restrict__ gp)
{
  __shared__ float tile[16][65];
  int t = threadIdx.x;
  int xc = blockIdx.x * 16;
  int y = blockIdx.y % HH, b = blockIdx.y / HH;
  #pragma unroll
  for (int cp = 0; cp < 4; ++cp) {
    int c = cp * 16 + (t >> 4);
    tile[t & 15][c] = src[((size_t)(b * 64 + c) * HH + y) * WW + xc + (t & 15)];
  }
  __syncthreads();
  int x = t >> 4, c4 = (t & 15) * 4;
  s16x4 s;
  #pragma unroll
  for (int j = 0; j < 4; ++j) s[j] = (short)f2bf(tile[x][c4 + j]);
  *(s16x4*)&concatT[((size_t)(b * HP + y + 1) * WPAD + xc + x + 1) * 128 + 64 + c4] = s;
  int g = c4 >> 3, co = c4 & 7;
  *(s16x4*)&gp[((size_t)(b * 8 + g) * HW_ + (size_t)y * WW + xc + x) * 8 + co] = s;
}

// ---------------------------------------------------------------------------
// MFMA implicit-GEMM 3x3 conv. Pixels staged once in LDS; per-tap weight
// SLICE staged via global_load_lds (DBUF: 1 barrier/tap) or, for the
// single-buffered case, REGPF: T14 async split — issue next tap's weights
// into REGISTERS before compute, ds_write after the barrier (latency hidden).
// OUTMODE 0: bf16 NCHW (K1) | 1: bf16 NHWC padded (K3) | 2: f32 NCHW + resid (K4)
// ---------------------------------------------------------------------------
template<int CIN, int COUT, int NF, bool LEAKY_, int OUTMODE, bool DBUF, bool REGPF>
__global__ __launch_bounds__(256, 4) void conv_mfma(
    const unsigned short* __restrict__ inT,   // [b][HP][WPAD][CIN] bf16
    const unsigned short* __restrict__ wS,    // [9][COUT][CIN] bf16, swizzled image
    const float* __restrict__ bias,
    const unsigned short* __restrict__ resid,
    void* __restrict__ outp)
{
  constexpr int CPP  = CIN / 8;          // 16B chunks per pixel
  constexpr int TPX  = 72;
  constexpr int NCH  = TPX * CPP;        // chunks per staged row
  constexpr int RPR  = NCH / 64;         // wave-regions per row
  constexpr int NREG = 3 * RPR;
  constexpr int WSZ  = NF * 16 * CIN;    // weight elems per tap slice
  constexpr int WCH  = WSZ / 8;          // 16B chunks per tap slice
  static_assert(WCH % 128 == 0, "staging must use full waves");
  static_assert(!REGPF || (WCH % 256 == 0), "REGPF needs whole chunks/thread");
  constexpr int RPT  = WCH / 256;        // reg-prefetch chunks per thread
  __shared__ __align__(16) unsigned short tile[3 * TPX * CIN];
  __shared__ __align__(16) unsigned short wlds[(DBUF ? 2 : 1) * WSZ];

  const int t = threadIdx.x;
  const int l = t & 63, wv = t >> 6;
  const int lr = l & 15, lq = l >> 4, lk = lq * 8;

  // XCD-aware bijective swizzle over the spatial grid (1152 % 8 == 0)
  constexpr int NWG = 3 * 384;
  int lin = blockIdx.x + 3 * blockIdx.y;
  int swz = (lin & 7) * (NWG / 8) + (lin >> 3);
  int xq = swz % 3, yy = swz / 3;
  int y = yy % HH, b = yy / HH;
  int x0 = xq * 64;
  const int co0 = blockIdx.z * (NF * 16);   // cout slice origin (mult of 16)

  // ---- stage 3 pixel rows (72 px each, swizzled) + weight tap-0 slice
  {
    const unsigned short* base = inT + ((size_t)(b * HP + y) * WPAD + x0) * CIN;
    for (int r = wv; r < NREG; r += 4) {
      int row = r / RPR;
      int rr  = r % RPR;
      int d   = rr * 64 + l;
      int p   = d / CPP;
      int cj  = d % CPP;
      int sc  = p * CPP + (cj ^ (p & (CPP - 1)));
      const unsigned short* src = base + (size_t)row * WPAD * CIN + (size_t)sc * 8;
      unsigned short* dst = &tile[(size_t)(row * NCH + rr * 64) * 8];
      __builtin_amdgcn_global_load_lds((GLB*)src, (LDS*)dst, 16, 0, 0);
    }
  }
  {
    const unsigned short* srcb = wS + (size_t)co0 * CIN;   // tap 0 slice
    for (int r = t; r < WCH; r += 256)
      __builtin_amdgcn_global_load_lds((GLB*)(srcb + (size_t)r * 8),
                                       (LDS*)(&wlds[(size_t)r * 8]), 16, 0, 0);
  }
  __syncthreads();

  f32x4 acc[NF];
  #pragma unroll
  for (int f = 0; f < NF; ++f) acc[f] = f32x4{0.f, 0.f, 0.f, 0.f};

  #pragma unroll
  for (int k = 0; k < 9; ++k) {
    const int ky = k / 3, kx = k % 3;
    if (DBUF && k < 8) {
      const unsigned short* srcb = wS + (size_t)(k + 1) * COUT * CIN + (size_t)co0 * CIN;
      unsigned short* db = &wlds[(size_t)((k + 1) & 1) * WSZ];
      for (int r = t; r < WCH; r += 256)
        __builtin_amdgcn_global_load_lds((GLB*)(srcb + (size_t)r * 8),
                                         (LDS*)(db + (size_t)r * 8), 16, 0, 0);
    }
    // REGPF: issue next tap's weight slice into registers BEFORE compute;
    // HBM/L2 latency hides under tap-k compute (T14 issue-early/write-late).
    u32x4 wpre[REGPF ? RPT : 1];
    if (REGPF && k < 8) {
      const unsigned short* srcb = wS + (size_t)(k + 1) * COUT * CIN + (size_t)co0 * CIN;
      #pragma unroll
      for (int r = 0; r < RPT; ++r)
        wpre[r] = *(const u32x4*)(srcb + (size_t)(t + r * 256) * 8);
    }
    // ---- compute tap k
    {
      const unsigned short* wb = &wlds[DBUF ? (size_t)(k & 1) * WSZ : 0];
      const int px = wv * 16 + lr + kx;
      #pragma unroll
      for (int c = 0; c < CIN; c += 32) {
        int cj = (c + lk) >> 3;
        bf16x8 pf = *(const bf16x8*)
            &tile[(size_t)(ky * NCH + px * CPP + (cj ^ (px & (CPP - 1)))) * 8];
        #pragma unroll
        for (int f = 0; f < NF; ++f) {
          int co = f * 16 + lr;             // local row; (co0+co)&7 == co&7
          bf16x8 wf = *(const bf16x8*)&wb[(size_t)co * CIN + ((cj ^ (co & 7)) << 3)];
          if (OUTMODE == 0)
            acc[f] = __builtin_amdgcn_mfma_f32_16x16x32_bf16(pf, wf, acc[f], 0, 0, 0);
          else
            acc[f] = __builtin_amdgcn_mfma_f32_16x16x32_bf16(wf, pf, acc[f], 0, 0, 0);
        }
      }
    }
    if (DBUF) {
      __syncthreads();
    } else if (REGPF) {
      if (k < 8) {
        __syncthreads();                     // all reads of wlds done
        #pragma unroll
        for (int r = 0; r < RPT; ++r)
          *(u32x4*)&wlds[(size_t)(t + r * 256) * 8] = wpre[r];
        __syncthreads();                     // new weights visible
      }
    } else if (k < 8) {
      __syncthreads();                       // all reads of wlds done
      const unsigned short* srcb = wS + (size_t)(k + 1) * COUT * CIN + (size_t)co0 * CIN;
      for (int r = t; r < WCH; r += 256)
        __builtin_amdgcn_global_load_lds((GLB*)(srcb + (size_t)r * 8),
                                         (LDS*)(&wlds[(size_t)r * 8]), 16, 0, 0);
      __syncthreads();                       // staging complete
    }
  }

  if (OUTMODE == 0) {
    int xs = x0 + wv * 16 + lq * 4;
    #pragma unroll
    for (int f = 0; f < NF; ++f) {
      int coG = co0 + f * 16 + lr;
      float bv = bias[coG];
      s16x4 s;
      #pragma unroll
      for (int j = 0; j < 4; ++j) {
        float v = acc[f][j] + bv;
        if (LEAKY_) v = leaky(v);
        s[j] = (short)f2bf(v);
      }
      *(s16x4*)((unsigned short*)outp + ((size_t)(b * COUT + coG) * HH + y) * WW + xs) = s;
    }
  } else if (OUTMODE == 1) {
    int x = x0 + wv * 16 + lr;
    #pragma unroll
    for (int f = 0; f < NF; ++f) {
      int coG = co0 + f * 16 + lq * 4;
      f32x4 bv = *(const f32x4*)&bias[coG];
      s16x4 s;
      #pragma unroll
      for (int j = 0; j < 4; ++j) {
        float v = acc[f][j] + bv[j];
        if (LEAKY_) v = leaky(v);
        s[j] = (short)f2bf(v);
      }
      *(s16x4*)((unsigned short*)outp + ((size_t)(b * HP + y + 1) * WPAD + x + 1) * 64 + coG) = s;
    }
  } else {
    int x = x0 + wv * 16 + lr;
    const unsigned short* rbase = resid + ((size_t)(b * HP + y + 1) * WPAD + x + 1) * 128;
    float* ob = (float*)outp + (size_t)b * 64 * HW_ + (size_t)y * WW + x;
    #pragma unroll
    for (int f = 0; f < NF; ++f) {
      int cobG = co0 + f * 16 + lq * 4;
      f32x4 bv = *(const f32x4*)&bias[cobG];
      s16x4 rv = *(const s16x4*)&rbase[cobG];
      #pragma unroll
      for (int j = 0; j < 4; ++j) {
        float v = acc[f][j] + bv[j];
        if (LEAKY_) v = leaky(v);
        v += bf2f((unsigned short)rv[j]);
        ob[(size_t)(cobG + j) * HW_] = v;
      }
    }
  }
}

// ---------------------------------------------------------------------------
// Deformable conv (R11-proven: passes both validations). LDS-window, 2x32
// tile, 2048-slot full-wave staging, group stride 241 slots.
// ---------------------------------------------------------------------------
__global__ __launch_bounds__(256, 4) void deform_mfma(
    const unsigned short* __restrict__ gp,    // [b][8][192][192][8] bf16
    const unsigned short* __restrict__ off,   // [b][144][192][192] bf16
    const unsigned short* __restrict__ wD,    // [9][64][64] bf16 plain
    const float* __restrict__ bias,
    unsigned short* __restrict__ concatT)     // [b][HP][WPAD][128], writes ch0-63
{
  __shared__ __align__(16) unsigned short win[2048 * 8];   // 32768 B
  const int t = threadIdx.x;
  const int l = t & 63, wv = t >> 6;
  const int lr = l & 15, lq = l >> 4;

  int lin = blockIdx.x;                       // 1152 blocks
  int swz = (lin & 7) * 144 + (lin >> 3);     // XCD-aware bijective
  int xt = swz % 6;
  int rest = swz / 6;                         // 0..191
  int yp = rest % 96, b = rest / 96;
  int Y = yp * 2, x0 = xt * 32;
  int yrow = Y + (wv >> 1);                   // this wave's output row
  int xpix = x0 + (wv & 1) * 16 + lr;         // this lane's pixel

  const int wy = Y - 2, wx = x0 - 3;          // window origin (image coords)
  const unsigned short* gpb = gp + (size_t)b * 8 * HW_ * 8;

  // ---- stage window: 2048 slots x 16B, all waves FULLY ACTIVE each iter
  #pragma unroll
  for (int i = 0; i < 8; ++i) {
    int p  = t + i * 256;                     // 0..2047
    int g  = min(p / 241, 7);
    int rc = p - g * 241;
    int rcc = min(rc, 239);                   // pad slots -> clamped source
    int r  = rcc / 40;
    int c  = rcc - r * 40;
    int yr = min(max(wy + r, 0), HH - 1);
    int xc = min(max(wx + c, 0), WW - 1);
    const unsigned short* src = gpb + ((size_t)g * HW_ + (size_t)yr * WW + xc) * 8;
    __builtin_amdgcn_global_load_lds((GLB*)src,
                                     (LDS*)(win + (size_t)p * 8), 16, 0, 0);
  }

  // ---- preload offsets, packed (dy | dx<<16) per (group-pair, tap)
  unsigned dd[2][9];
  #pragma unroll
  for (int gi = 0; gi < 2; ++gi) {
    int g = lq + gi * 4;
    const unsigned short* op = off + ((size_t)(b * 144 + g * 18) * HH + yrow) * WW + xpix;
    #pragma unroll
    for (int k = 0; k < 9; ++k) {
      unsigned dyv = op[(size_t)(2 * k) * HW_];
      unsigned dxv = op[(size_t)(2 * k + 1) * HW_];
      dd[gi][k] = dyv | (dxv << 16);
    }
  }

  __syncthreads();                            // window ready (single barrier)

  f32x4 acc[4];
  #pragma unroll
  for (int f = 0; f < 4; ++f) acc[f] = f32x4{0.f, 0.f, 0.f, 0.f};

  #pragma unroll
  for (int k = 0; k < 9; ++k) {
    const int ky = k / 3, kx = k % 3;
    bf16x8 pf0, pf1;
    #pragma unroll
    for (int gi = 0; gi < 2; ++gi) {
      int g = lq + gi * 4;
      float dyv = bf2f((unsigned short)(dd[gi][k] & 0xffffu));
      float dxv = bf2f((unsigned short)(dd[gi][k] >> 16));
      float py = (float)(yrow - 1 + ky) + dyv;
      float px = (float)(xpix - 1 + kx) + dxv;
      float fy0 = floorf(py), fx0 = floorf(px);
      float wy1 = py - fy0, wx1 = px - fx0;
      float wy0 = 1.f - wy1, wx0 = 1.f - wx1;
      bool vy0 = (fy0 >= 0.f)  && (fy0 <= 191.f);
      bool vy1 = (fy0 >= -1.f) && (fy0 <= 190.f);
      bool vx0 = (fx0 >= 0.f)  && (fx0 <= 191.f);
      bool vx1 = (fx0 >= -1.f) && (fx0 <= 190.f);
      float c00 = (vy0 && vx0) ? wy0 * wx0 : 0.f;
      float c01 = (vy0 && vx1) ? wy0 * wx1 : 0.f;
      float c10 = (vy1 && vx0) ? wy1 * wx0 : 0.f;
      float c11 = (vy1 && vx1) ? wy1 * wx1 : 0.f;
      int iy0 = (int)fminf(fmaxf(fy0, 0.f), 191.f);
      int iy1 = (int)fminf(fmaxf(fy0 + 1.f, 0.f), 191.f);
      int ix0 = (int)fminf(fmaxf(fx0, 0.f), 191.f);
      int ix1 = (int)fminf(fmaxf(fx0 + 1.f, 0.f), 191.f);
      bool inw = (iy0 >= wy) && (iy1 <= wy + 5) && (ix0 >= wx) && (ix1 <= wx + 39);
      int ry0 = min(max(iy0 - wy, 0), 5), ry1 = min(max(iy1 - wy, 0), 5);
      int rx0 = min(max(ix0 - wx, 0), 39), rx1 = min(max(ix1 - wx, 0), 39);
      const unsigned short* wg = win + (size_t)g * (241 * 8);
      bf16x8 v00 = *(const bf16x8*)(wg + ((size_t)ry0 * 40 + rx0) * 8);
      bf16x8 v01 = *(const bf16x8*)(wg + ((size_t)ry0 * 40 + rx1) * 8);
      bf16x8 v10 = *(const bf16x8*)(wg + ((size_t)ry1 * 40 + rx0) * 8);
      bf16x8 v11 = *(const bf16x8*)(wg + ((size_t)ry1 * 40 + rx1) * 8);
      if (!__all((int)inw)) {                 // rare: exact global fallback
        if (!inw) {
          const unsigned short* bb = gpb + (size_t)g * HW_ * 8;
          v00 = *(const bf16x8*)(bb + ((size_t)iy0 * WW + ix0) * 8);
          v01 = *(const bf16x8*)(bb + ((size_t)iy0 * WW + ix1) * 8);
          v10 = *(const bf16x8*)(bb + ((size_t)iy1 * WW + ix0) * 8);
          v11 = *(const bf16x8*)(bb + ((size_t)iy1 * WW + ix1) * 8);
        }
      }
      bf16x8 sv;
      #pragma unroll
      for (int j = 0; j < 8; ++j) {
        float s = bf2f((unsigned short)v00[j]) * c00
                + bf2f((unsigned short)v01[j]) * c01
                + bf2f((unsigned short)v10[j]) * c10
                + bf2f((unsigned short)v11[j]) * c11;
        sv[j] = (short)f2bf(s);
      }
      if (gi == 0) pf0 = sv; else pf1 = sv;
    }
    #pragma unroll
    for (int f = 0; f < 4; ++f) {
      bf16x8 wf = *(const bf16x8*)&wD[((size_t)k * 64 + f * 16 + lr) * 64 + lq * 8];
      acc[f] = __builtin_amdgcn_mfma_f32_16x16x32_bf16(wf, pf0, acc[f], 0, 0, 0);
    }
    #pragma unroll
    for (int f = 0; f < 4; ++f) {
      bf16x8 wf = *(const bf16x8*)&wD[((size_t)k * 64 + f * 16 + lr) * 64 + 32 + lq * 8];
      acc[f] = __builtin_amdgcn_mfma_f32_16x16x32_bf16(wf, pf1, acc[f], 0, 0, 0);
    }
  }

  // epilogue: NHWC bf16 into concat channels [0,64)
  unsigned short* outc = concatT + (size_t)b * HP * WPAD * 128;
  #pragma unroll
  for (int f = 0; f < 4; ++f) {
    int co = f * 16 + lq * 4;
    f32x4 bv = *(const f32x4*)&bias[co];
    s16x4 s;
    #pragma unroll
    for (int j = 0; j < 4; ++j) s[j] = (short)f2bf(acc[f][j] + bv[j]);
    *(s16x4*)&outc[((size_t)(yrow + 1) * WPAD + xpix + 1) * 128 + co] = s;
  }
}

// ---------------------------------------------------------------------------
extern "C" void kernel_launch(void* const* d_in, const int* in_sizes, int n_in,
                              void* d_out, int out_size, void* d_ws, size_t ws_size,
                              hipStream_t stream)
{
  const float* prev  = (const float*)d_in[0];
  const float* offin = (const float*)d_in[1];
  const float* w_off = (const float*)d_in[2];
  const float* b_off = (const float*)d_in[3];
  const float* w_dcn = (const float*)d_in[4];
  const float* b_dcn = (const float*)d_in[5];
  const float* w_r1  = (const float*)d_in[6];
  const float* b_r1  = (const float*)d_in[7];
  const float* w_r2  = (const float*)d_in[8];
  const float* b_r2  = (const float*)d_in[9];
  float* out = (float*)d_out;

  char* p = (char*)d_ws;
  unsigned short* offs_t   = (unsigned short*)p; p += (size_t)B_ * HP * WPAD * 64 * 2;   //  9.93 MB
  unsigned short* concat_t = (unsigned short*)p; p += (size_t)B_ * HP * WPAD * 128 * 2;  // 19.87 MB
  unsigned short* r1_t     = (unsigned short*)p; p += (size_t)B_ * HP * WPAD * 64 * 2;   //  9.93 MB
  unsigned short* offf     = (unsigned short*)p; p += (size_t)B_ * 144 * HW_ * 2;        // 21.23 MB
  unsigned short* wOffB    = (unsigned short*)p; p += 144 * 576 * 2;
  unsigned short* wDcnB    = (unsigned short*)p; p += 64 * 576 * 2;
  unsigned short* wR1B     = (unsigned short*)p; p += 64 * 1152 * 2;
  unsigned short* wR2B     = (unsigned short*)p; p += 64 * 576 * 2;                      // total ~61.4 MB
  // gp aliases offs_t: offs_t is dead after K1; prep_prev runs after K1.
  unsigned short* gp = offs_t;

  // prep0: offsets->NHWC + weight transforms + border zeroing (fused)
  prep0<<<5812, 256, 0, stream>>>(offin, w_off, w_dcn, w_r1, w_r2,
                                  offs_t, concat_t, r1_t,
                                  wOffB, wDcnB, wR1B, wR2B);

  // K1: offset conv (64 -> 144), cout-split x3 (grid 3456), DBUF.
  conv_mfma<64, 144, 3, false, 0, true, false><<<dim3(3, 384, 3), 256, 0, stream>>>(
      offs_t, wOffB, b_off, nullptr, offf);

  // prev -> concat ch[64,128) + group-planar gp (fused; overwrites offs_t)
  prep_prev<<<dim3(12, 384), 256, 0, stream>>>(prev, concat_t, gp);

  // K2: deformable conv -> concat_t channels [0,64).
  deform_mfma<<<1152, 256, 0, stream>>>(gp, offf, wDcnB, b_dcn, concat_t);

  // K3: r1 = leaky(conv(concat)) (128 -> 64), full cout, REGPF (T14 split).
  conv_mfma<128, 64, 4, true, 1, false, true><<<dim3(3, 384, 1), 256, 0, stream>>>(
      concat_t, wR1B, b_r1, nullptr, r1_t);

  // K4: out = aligned + leaky(conv(r1)) (64 -> 64), full cout, DBUF.
  conv_mfma<64, 64, 4, true, 2, true, false><<<dim3(3, 384, 1), 256, 0, stream>>>(
      r1_t, wR2B, b_r2, concat_t, out);
}

// Round 16
// 138.150 us; speedup vs baseline: 1.1345x; 1.0493x over previous
//
#include <hip/hip_runtime.h>
#include <hip/hip_bf16.h>
#include <cstdint>
#include <cstddef>

constexpr int B_ = 2;
constexpr int HH = 192, WW = 192, HW_ = HH * WW;
constexpr int HP = 194, WPAD = 200;   // padded dims

typedef short bf16x8 __attribute__((ext_vector_type(8)));
typedef short s16x4  __attribute__((ext_vector_type(4)));
typedef float f32x4  __attribute__((ext_vector_type(4)));
typedef unsigned int u32x4 __attribute__((ext_vector_type(4)));

typedef __attribute__((address_space(1))) const void GLB;
typedef __attribute__((address_space(3))) void LDS;

__device__ __forceinline__ float bf2f(unsigned short h) {
  union { unsigned u; float f; } v; v.u = (unsigned)h << 16; return v.f;
}
__device__ __forceinline__ unsigned short f2bf(float f) {
  union { float f; unsigned u; } v; v.f = f;
  unsigned u = v.u;
  u += 0x7fffu + ((u >> 16) & 1u);
  return (unsigned short)(u >> 16);
}
__device__ __forceinline__ float leaky(float v) { return fmaxf(v, 0.1f * v); }

// ---------------------------------------------------------------------------
// prep0: fused (a) offsets NCHW->NHWC, (b) weight transforms, (c) border zero
// of offs_t + concat_t (r1_t borders are re-zeroed in K3 — gp clobbers them).
// ---------------------------------------------------------------------------
__global__ __launch_bounds__(256) void prep0(
    const float* __restrict__ offin,
    const float* __restrict__ w_off, const float* __restrict__ w_dcn,
    const float* __restrict__ w_r1,  const float* __restrict__ w_r2,
    unsigned short* __restrict__ offs_t, unsigned short* __restrict__ concat_t,
    unsigned short* __restrict__ wOffB, unsigned short* __restrict__ wDcnB,
    unsigned short* __restrict__ wR1B,  unsigned short* __restrict__ wR2B)
{
  __shared__ float tile[16][65];
  int bid = blockIdx.x;
  int t = threadIdx.x;

  if (bid < 4608) {
    int bx = bid % 12, by = bid / 12;
    int xc = bx * 16;
    int y = by % HH, b = by / HH;
    #pragma unroll
    for (int cp = 0; cp < 4; ++cp) {
      int c = cp * 16 + (t >> 4);
      tile[t & 15][c] = offin[((size_t)(b * 64 + c) * HH + y) * WW + xc + (t & 15)];
    }
    __syncthreads();
    int x = t >> 4, c4 = (t & 15) * 4;
    s16x4 s;
    #pragma unroll
    for (int j = 0; j < 4; ++j) s[j] = (short)f2bf(tile[x][c4 + j]);
    *(s16x4*)&offs_t[((size_t)(b * HP + y + 1) * WPAD + xc + x + 1) * 64 + c4] = s;
  } else if (bid < 5508) {
    int tid = (bid - 4608) * 256 + t;           // [0, 230400)
    const float* src; unsigned short* dst; int CI, CO, idx; bool dosw = true;
    if (tid < 82944)       { src = w_off; dst = wOffB; CI = 64;  CO = 144; idx = tid; }
    else if (tid < 119808) { src = w_dcn; dst = wDcnB; CI = 64;  CO = 64;  idx = tid - 82944; dosw = false; }
    else if (tid < 193536) { src = w_r1;  dst = wR1B;  CI = 128; CO = 64;  idx = tid - 119808; }
    else                   { src = w_r2;  dst = wR2B;  CI = 64;  CO = 64;  idx = tid - 193536; }
    int ci = idx % CI;
    int k  = (idx / CI) % 9;
    int o  = idx / (CI * 9);
    int pci = dosw ? (((((ci >> 3) ^ (o & 7))) << 3) | (ci & 7)) : ci;
    dst[((size_t)k * CO + o) * CI + pci] = f2bf(src[((size_t)o * CI + ci) * 9 + k]);
  } else {
    int tid = (bid - 5508) * 256 + t;           // covers 77600
    if (tid >= B_ * HP * WPAD) return;
    int x = tid % WPAD, y = (tid / WPAD) % HP, b = tid / (HP * WPAD);
    bool border = (y == 0) || (y >= 193) || (x == 0) || (x >= 193);
    if (!border) return;
    size_t px = (size_t)(b * HP + y) * WPAD + x;
    u32x4 z4 = {0u, 0u, 0u, 0u};
    u32x4* p0 = (u32x4*)(offs_t   + px * 64);
    u32x4* p1 = (u32x4*)(concat_t + px * 128);
    #pragma unroll
    for (int i = 0; i < 8; ++i)  p0[i] = z4;
    #pragma unroll
    for (int i = 0; i < 16; ++i) p1[i] = z4;
  }
}

// ---------------------------------------------------------------------------
// prep_prev body: prev NCHW f32 -> concat_t ch[64,128) + group-planar gp.
// (called from the fused K1 dispatch; tile memory borrowed from conv's LDS)
// ---------------------------------------------------------------------------
__device__ __forceinline__ void prep_prev_body(
    const float* __restrict__ src, unsigned short* __restrict__ concatT,
    unsigned short* __restrict__ gp, int bx, int by, float (*tile)[65], int t)
{
  int xc = bx * 16;
  int y = by % HH, b = by / HH;
  #pragma unroll
  for (int cp = 0; cp < 4; ++cp) {
    int c = cp * 16 + (t >> 4);
    tile[t & 15][c] = src[((size_t)(b * 64 + c) * HH + y) * WW + xc + (t & 15)];
  }
  __syncthreads();
  int x = t >> 4, c4 = (t & 15) * 4;
  s16x4 s;
  #pragma unroll
  for (int j = 0; j < 4; ++j) s[j] = (short)f2bf(tile[x][c4 + j]);
  *(s16x4*)&concatT[((size_t)(b * HP + y + 1) * WPAD + xc + x + 1) * 128 + 64 + c4] = s;
  int g = c4 >> 3, co = c4 & 7;
  *(s16x4*)&gp[((size_t)(b * 8 + g) * HW_ + (size_t)y * WW + xc + x) * 8 + co] = s;
}

// ---------------------------------------------------------------------------
// MFMA implicit-GEMM 3x3 conv body (shared by K1/K3/K4 kernels).
// Pixels staged once in LDS; per-tap weight SLICE staged via global_load_lds
// (DBUF) or T14 reg-prefetch (REGPF). All staging trips are full waves.
// ---------------------------------------------------------------------------
template<int CIN, int COUT, int NF, bool LEAKY_, int OUTMODE, bool DBUF, bool REGPF>
__device__ __forceinline__ void conv_body(
    const unsigned short* __restrict__ inT,
    const unsigned short* __restrict__ wS,
    const float* __restrict__ bias,
    const unsigned short* __restrict__ resid,
    void* __restrict__ outp,
    unsigned short* tile, unsigned short* wlds, int co0)
{
  constexpr int CPP  = CIN / 8;
  constexpr int TPX  = 72;
  constexpr int NCH  = TPX * CPP;
  constexpr int RPR  = NCH / 64;
  constexpr int NREG = 3 * RPR;
  constexpr int WSZ  = NF * 16 * CIN;
  constexpr int WCH  = WSZ / 8;
  static_assert(WCH % 128 == 0, "staging must use full waves");
  static_assert(!REGPF || (WCH % 256 == 0), "REGPF needs whole chunks/thread");
  constexpr int RPT  = WCH / 256;

  const int t = threadIdx.x;
  const int l = t & 63, wv = t >> 6;
  const int lr = l & 15, lq = l >> 4, lk = lq * 8;

  constexpr int NWG = 3 * 384;
  int lin = blockIdx.x + 3 * blockIdx.y;
  int swz = (lin & 7) * (NWG / 8) + (lin >> 3);
  int xq = swz % 3, yy = swz / 3;
  int y = yy % HH, b = yy / HH;
  int x0 = xq * 64;

  {
    const unsigned short* base = inT + ((size_t)(b * HP + y) * WPAD + x0) * CIN;
    for (int r = wv; r < NREG; r += 4) {
      int row = r / RPR;
      int rr  = r % RPR;
      int d   = rr * 64 + l;
      int p   = d / CPP;
      int cj  = d % CPP;
      int sc  = p * CPP + (cj ^ (p & (CPP - 1)));
      const unsigned short* src = base + (size_t)row * WPAD * CIN + (size_t)sc * 8;
      unsigned short* dst = &tile[(size_t)(row * NCH + rr * 64) * 8];
      __builtin_amdgcn_global_load_lds((GLB*)src, (LDS*)dst, 16, 0, 0);
    }
  }
  {
    const unsigned short* srcb = wS + (size_t)co0 * CIN;
    for (int r = t; r < WCH; r += 256)
      __builtin_amdgcn_global_load_lds((GLB*)(srcb + (size_t)r * 8),
                                       (LDS*)(&wlds[(size_t)r * 8]), 16, 0, 0);
  }
  __syncthreads();

  f32x4 acc[NF];
  #pragma unroll
  for (int f = 0; f < NF; ++f) acc[f] = f32x4{0.f, 0.f, 0.f, 0.f};

  #pragma unroll
  for (int k = 0; k < 9; ++k) {
    const int ky = k / 3, kx = k % 3;
    if (DBUF && k < 8) {
      const unsigned short* srcb = wS + (size_t)(k + 1) * COUT * CIN + (size_t)co0 * CIN;
      unsigned short* db = &wlds[(size_t)((k + 1) & 1) * WSZ];
      for (int r = t; r < WCH; r += 256)
        __builtin_amdgcn_global_load_lds((GLB*)(srcb + (size_t)r * 8),
                                         (LDS*)(db + (size_t)r * 8), 16, 0, 0);
    }
    u32x4 wpre[REGPF ? RPT : 1];
    if (REGPF && k < 8) {
      const unsigned short* srcb = wS + (size_t)(k + 1) * COUT * CIN + (size_t)co0 * CIN;
      #pragma unroll
      for (int r = 0; r < RPT; ++r)
        wpre[r] = *(const u32x4*)(srcb + (size_t)(t + r * 256) * 8);
    }
    {
      const unsigned short* wb = &wlds[DBUF ? (size_t)(k & 1) * WSZ : 0];
      const int px = wv * 16 + lr + kx;
      #pragma unroll
      for (int c = 0; c < CIN; c += 32) {
        int cj = (c + lk) >> 3;
        bf16x8 pf = *(const bf16x8*)
            &tile[(size_t)(ky * NCH + px * CPP + (cj ^ (px & (CPP - 1)))) * 8];
        #pragma unroll
        for (int f = 0; f < NF; ++f) {
          int co = f * 16 + lr;
          bf16x8 wf = *(const bf16x8*)&wb[(size_t)co * CIN + ((cj ^ (co & 7)) << 3)];
          if (OUTMODE == 0)
            acc[f] = __builtin_amdgcn_mfma_f32_16x16x32_bf16(pf, wf, acc[f], 0, 0, 0);
          else
            acc[f] = __builtin_amdgcn_mfma_f32_16x16x32_bf16(wf, pf, acc[f], 0, 0, 0);
        }
      }
    }
    if (DBUF) {
      __syncthreads();
    } else if (REGPF) {
      if (k < 8) {
        __syncthreads();
        #pragma unroll
        for (int r = 0; r < RPT; ++r)
          *(u32x4*)&wlds[(size_t)(t + r * 256) * 8] = wpre[r];
        __syncthreads();
      }
    } else if (k < 8) {
      __syncthreads();
      const unsigned short* srcb = wS + (size_t)(k + 1) * COUT * CIN + (size_t)co0 * CIN;
      for (int r = t; r < WCH; r += 256)
        __builtin_amdgcn_global_load_lds((GLB*)(srcb + (size_t)r * 8),
                                         (LDS*)(&wlds[(size_t)r * 8]), 16, 0, 0);
      __syncthreads();
    }
  }

  if (OUTMODE == 0) {
    int xs = x0 + wv * 16 + lq * 4;
    #pragma unroll
    for (int f = 0; f < NF; ++f) {
      int coG = co0 + f * 16 + lr;
      float bv = bias[coG];
      s16x4 s;
      #pragma unroll
      for (int j = 0; j < 4; ++j) {
        float v = acc[f][j] + bv;
        if (LEAKY_) v = leaky(v);
        s[j] = (short)f2bf(v);
      }
      *(s16x4*)((unsigned short*)outp + ((size_t)(b * COUT + coG) * HH + y) * WW + xs) = s;
    }
  } else if (OUTMODE == 1) {
    int x = x0 + wv * 16 + lr;
    #pragma unroll
    for (int f = 0; f < NF; ++f) {
      int coG = co0 + f * 16 + lq * 4;
      f32x4 bv = *(const f32x4*)&bias[coG];
      s16x4 s;
      #pragma unroll
      for (int j = 0; j < 4; ++j) {
        float v = acc[f][j] + bv[j];
        if (LEAKY_) v = leaky(v);
        s[j] = (short)f2bf(v);
      }
      *(s16x4*)((unsigned short*)outp + ((size_t)(b * HP + y + 1) * WPAD + x + 1) * 64 + coG) = s;
    }
  } else {
    int x = x0 + wv * 16 + lr;
    const unsigned short* rbase = resid + ((size_t)(b * HP + y + 1) * WPAD + x + 1) * 128;
    float* ob = (float*)outp + (size_t)b * 64 * HW_ + (size_t)y * WW + x;
    #pragma unroll
    for (int f = 0; f < NF; ++f) {
      int cobG = co0 + f * 16 + lq * 4;
      f32x4 bv = *(const f32x4*)&bias[cobG];
      s16x4 rv = *(const s16x4*)&rbase[cobG];
      #pragma unroll
      for (int j = 0; j < 4; ++j) {
        float v = acc[f][j] + bv[j];
        if (LEAKY_) v = leaky(v);
        v += bf2f((unsigned short)rv[j]);
        ob[(size_t)(cobG + j) * HW_] = v;
      }
    }
  }
}

// ---------------------------------------------------------------------------
// K1 fused: z<3 = offset conv slices (co0 = z*48); z in [3,7) = prep_prev
// (prev -> concat ch64-127 + gp). Safe because gp now aliases r1_t, which
// nothing reads/writes until K3 (offs_t is no longer clobbered).
// ---------------------------------------------------------------------------
__global__ __launch_bounds__(256, 4) void k1_fused(
    const unsigned short* __restrict__ offs_t,
    const unsigned short* __restrict__ wOffB,
    const float* __restrict__ b_off,
    unsigned short* __restrict__ offf,
    const float* __restrict__ prev,
    unsigned short* __restrict__ concat_t,
    unsigned short* __restrict__ gp)
{
  __shared__ __align__(16) unsigned short tile[3 * 72 * 64];   // 27648 B
  __shared__ __align__(16) unsigned short wlds[2 * 3 * 16 * 64];
  int z = blockIdx.z;
  if (z < 3) {
    conv_body<64, 144, 3, false, 0, true, false>(
        offs_t, wOffB, b_off, nullptr, offf, tile, wlds, z * 48);
  } else {
    int pid = (z - 3) * 1152 + blockIdx.x + 3 * blockIdx.y;    // [0, 4608)
    prep_prev_body(prev, concat_t, gp, pid % 12, pid / 12,
                   (float(*)[65])tile, threadIdx.x);
  }
}

// ---------------------------------------------------------------------------
// K3: z==0 = conv (concat 128 -> 64, REGPF); z==1 = border-zero r1_t
// (gp writes clobbered the prep0 zeros; K2 is done with gp by now).
// ---------------------------------------------------------------------------
__global__ __launch_bounds__(256, 4) void conv_k3(
    const unsigned short* __restrict__ concat_t,
    const unsigned short* __restrict__ wR1B,
    const float* __restrict__ b_r1,
    unsigned short* __restrict__ r1_t)
{
  __shared__ __align__(16) unsigned short tile[3 * 72 * 128];  // 55296 B
  __shared__ __align__(16) unsigned short wlds[4 * 16 * 128];  // 16384 B
  if (blockIdx.z == 1) {
    int tid = (blockIdx.x + 3 * blockIdx.y) * 256 + threadIdx.x;
    if (tid >= B_ * HP * WPAD) return;
    int x = tid % WPAD, y = (tid / WPAD) % HP, b = tid / (HP * WPAD);
    bool border = (y == 0) || (y >= 193) || (x == 0) || (x >= 193);
    if (!border) return;
    u32x4 z4 = {0u, 0u, 0u, 0u};
    u32x4* p2 = (u32x4*)(r1_t + ((size_t)(b * HP + y) * WPAD + x) * 64);
    #pragma unroll
    for (int i = 0; i < 8; ++i) p2[i] = z4;
    return;
  }
  conv_body<128, 64, 4, true, 1, false, true>(
      concat_t, wR1B, b_r1, nullptr, r1_t, tile, wlds, 0);
}

// ---------------------------------------------------------------------------
// K4: out = aligned + leaky(conv(r1)), DBUF.
// ---------------------------------------------------------------------------
__global__ __launch_bounds__(256, 4) void conv_k4(
    const unsigned short* __restrict__ r1_t,
    const unsigned short* __restrict__ wR2B,
    const float* __restrict__ b_r2,
    const unsigned short* __restrict__ concat_t,
    float* __restrict__ out)
{
  __shared__ __align__(16) unsigned short tile[3 * 72 * 64];
  __shared__ __align__(16) unsigned short wlds[2 * 4 * 16 * 64];
  conv_body<64, 64, 4, true, 2, true, false>(
      r1_t, wR2B, b_r2, concat_t, out, tile, wlds, 0);
}

// ---------------------------------------------------------------------------
// Deformable conv (R11-proven). LDS-window, 2x32 tile, 2048-slot full-wave
// staging, group stride 241 slots.
// ---------------------------------------------------------------------------
__global__ __launch_bounds__(256, 4) void deform_mfma(
    const unsigned short* __restrict__ gp,    // [b][8][192][192][8] bf16
    const unsigned short* __restrict__ off,   // [b][144][192][192] bf16
    const unsigned short* __restrict__ wD,    // [9][64][64] bf16 plain
    const float* __restrict__ bias,
    unsigned short* __restrict__ concatT)     // [b][HP][WPAD][128], writes ch0-63
{
  __shared__ __align__(16) unsigned short win[2048 * 8];   // 32768 B
  const int t = threadIdx.x;
  const int l = t & 63, wv = t >> 6;
  const int lr = l & 15, lq = l >> 4;

  int lin = blockIdx.x;                       // 1152 blocks
  int swz = (lin & 7) * 144 + (lin >> 3);     // XCD-aware bijective
  int xt = swz % 6;
  int rest = swz / 6;                         // 0..191
  int yp = rest % 96, b = rest / 96;
  int Y = yp * 2, x0 = xt * 32;
  int yrow = Y + (wv >> 1);
  int xpix = x0 + (wv & 1) * 16 + lr;

  const int wy = Y - 2, wx = x0 - 3;
  const unsigned short* gpb = gp + (size_t)b * 8 * HW_ * 8;

  #pragma unroll
  for (int i = 0; i < 8; ++i) {
    int p  = t + i * 256;
    int g  = min(p / 241, 7);
    int rc = p - g * 241;
    int rcc = min(rc, 239);
    int r  = rcc / 40;
    int c  = rcc - r * 40;
    int yr = min(max(wy + r, 0), HH - 1);
    int xc = min(max(wx + c, 0), WW - 1);
    const unsigned short* src = gpb + ((size_t)g * HW_ + (size_t)yr * WW + xc) * 8;
    __builtin_amdgcn_global_load_lds((GLB*)src,
                                     (LDS*)(win + (size_t)p * 8), 16, 0, 0);
  }

  unsigned dd[2][9];
  #pragma unroll
  for (int gi = 0; gi < 2; ++gi) {
    int g = lq + gi * 4;
    const unsigned short* op = off + ((size_t)(b * 144 + g * 18) * HH + yrow) * WW + xpix;
    #pragma unroll
    for (int k = 0; k < 9; ++k) {
      unsigned dyv = op[(size_t)(2 * k) * HW_];
      unsigned dxv = op[(size_t)(2 * k + 1) * HW_];
      dd[gi][k] = dyv | (dxv << 16);
    }
  }

  __syncthreads();

  f32x4 acc[4];
  #pragma unroll
  for (int f = 0; f < 4; ++f) acc[f] = f32x4{0.f, 0.f, 0.f, 0.f};

  #pragma unroll
  for (int k = 0; k < 9; ++k) {
    const int ky = k / 3, kx = k % 3;
    bf16x8 pf0, pf1;
    #pragma unroll
    for (int gi = 0; gi < 2; ++gi) {
      int g = lq + gi * 4;
      float dyv = bf2f((unsigned short)(dd[gi][k] & 0xffffu));
      float dxv = bf2f((unsigned short)(dd[gi][k] >> 16));
      float py = (float)(yrow - 1 + ky) + dyv;
      float px = (float)(xpix - 1 + kx) + dxv;
      float fy0 = floorf(py), fx0 = floorf(px);
      float wy1 = py - fy0, wx1 = px - fx0;
      float wy0 = 1.f - wy1, wx0 = 1.f - wx1;
      bool vy0 = (fy0 >= 0.f)  && (fy0 <= 191.f);
      bool vy1 = (fy0 >= -1.f) && (fy0 <= 190.f);
      bool vx0 = (fx0 >= 0.f)  && (fx0 <= 191.f);
      bool vx1 = (fx0 >= -1.f) && (fx0 <= 190.f);
      float c00 = (vy0 && vx0) ? wy0 * wx0 : 0.f;
      float c01 = (vy0 && vx1) ? wy0 * wx1 : 0.f;
      float c10 = (vy1 && vx0) ? wy1 * wx0 : 0.f;
      float c11 = (vy1 && vx1) ? wy1 * wx1 : 0.f;
      int iy0 = (int)fminf(fmaxf(fy0, 0.f), 191.f);
      int iy1 = (int)fminf(fmaxf(fy0 + 1.f, 0.f), 191.f);
      int ix0 = (int)fminf(fmaxf(fx0, 0.f), 191.f);
      int ix1 = (int)fminf(fmaxf(fx0 + 1.f, 0.f), 191.f);
      bool inw = (iy0 >= wy) && (iy1 <= wy + 5) && (ix0 >= wx) && (ix1 <= wx + 39);
      int ry0 = min(max(iy0 - wy, 0), 5), ry1 = min(max(iy1 - wy, 0), 5);
      int rx0 = min(max(ix0 - wx, 0), 39), rx1 = min(max(ix1 - wx, 0), 39);
      const unsigned short* wg = win + (size_t)g * (241 * 8);
      bf16x8 v00 = *(const bf16x8*)(wg + ((size_t)ry0 * 40 + rx0) * 8);
      bf16x8 v01 = *(const bf16x8*)(wg + ((size_t)ry0 * 40 + rx1) * 8);
      bf16x8 v10 = *(const bf16x8*)(wg + ((size_t)ry1 * 40 + rx0) * 8);
      bf16x8 v11 = *(const bf16x8*)(wg + ((size_t)ry1 * 40 + rx1) * 8);
      if (!__all((int)inw)) {
        if (!inw) {
          const unsigned short* bb = gpb + (size_t)g * HW_ * 8;
          v00 = *(const bf16x8*)(bb + ((size_t)iy0 * WW + ix0) * 8);
          v01 = *(const bf16x8*)(bb + ((size_t)iy0 * WW + ix1) * 8);
          v10 = *(const bf16x8*)(bb + ((size_t)iy1 * WW + ix0) * 8);
          v11 = *(const bf16x8*)(bb + ((size_t)iy1 * WW + ix1) * 8);
        }
      }
      bf16x8 sv;
      #pragma unroll
      for (int j = 0; j < 8; ++j) {
        float s = bf2f((unsigned short)v00[j]) * c00
                + bf2f((unsigned short)v01[j]) * c01
                + bf2f((unsigned short)v10[j]) * c10
                + bf2f((unsigned short)v11[j]) * c11;
        sv[j] = (short)f2bf(s);
      }
      if (gi == 0) pf0 = sv; else pf1 = sv;
    }
    #pragma unroll
    for (int f = 0; f < 4; ++f) {
      bf16x8 wf = *(const bf16x8*)&wD[((size_t)k * 64 + f * 16 + lr) * 64 + lq * 8];
      acc[f] = __builtin_amdgcn_mfma_f32_16x16x32_bf16(wf, pf0, acc[f], 0, 0, 0);
    }
    #pragma unroll
    for (int f = 0; f < 4; ++f) {
      bf16x8 wf = *(const bf16x8*)&wD[((size_t)k * 64 + f * 16 + lr) * 64 + 32 + lq * 8];
      acc[f] = __builtin_amdgcn_mfma_f32_16x16x32_bf16(wf, pf1, acc[f], 0, 0, 0);
    }
  }

  unsigned short* outc = concatT + (size_t)b * HP * WPAD * 128;
  #pragma unroll
  for (int f = 0; f < 4; ++f) {
    int co = f * 16 + lq * 4;
    f32x4 bv = *(const f32x4*)&bias[co];
    s16x4 s;
    #pragma unroll
    for (int j = 0; j < 4; ++j) s[j] = (short)f2bf(acc[f][j] + bv[j]);
    *(s16x4*)&outc[((size_t)(yrow + 1) * WPAD + xpix + 1) * 128 + co] = s;
  }
}

// ---------------------------------------------------------------------------
extern "C" void kernel_launch(void* const* d_in, const int* in_sizes, int n_in,
                              void* d_out, int out_size, void* d_ws, size_t ws_size,
                              hipStream_t stream)
{
  const float* prev  = (const float*)d_in[0];
  const float* offin = (const float*)d_in[1];
  const float* w_off = (const float*)d_in[2];
  const float* b_off = (const float*)d_in[3];
  const float* w_dcn = (const float*)d_in[4];
  const float* b_dcn = (const float*)d_in[5];
  const float* w_r1  = (const float*)d_in[6];
  const float* b_r1  = (const float*)d_in[7];
  const float* w_r2  = (const float*)d_in[8];
  const float* b_r2  = (const float*)d_in[9];
  float* out = (float*)d_out;

  char* p = (char*)d_ws;
  unsigned short* offs_t   = (unsigned short*)p; p += (size_t)B_ * HP * WPAD * 64 * 2;   //  9.93 MB
  unsigned short* concat_t = (unsigned short*)p; p += (size_t)B_ * HP * WPAD * 128 * 2;  // 19.87 MB
  unsigned short* r1_t     = (unsigned short*)p; p += (size_t)B_ * HP * WPAD * 64 * 2;   //  9.93 MB
  unsigned short* offf     = (unsigned short*)p; p += (size_t)B_ * 144 * HW_ * 2;        // 21.23 MB
  unsigned short* wOffB    = (unsigned short*)p; p += 144 * 576 * 2;
  unsigned short* wDcnB    = (unsigned short*)p; p += 64 * 576 * 2;
  unsigned short* wR1B     = (unsigned short*)p; p += 64 * 1152 * 2;
  unsigned short* wR2B     = (unsigned short*)p; p += 64 * 576 * 2;                      // total ~61.4 MB
  // gp (9.44 MB) aliases r1_t (9.93 MB): written by k1_fused's prep slices,
  // read by K2, then overwritten by K3 (whose z=1 slice re-zeros the borders).
  unsigned short* gp = r1_t;

  // prep0: offsets->NHWC + weight transforms + offs/concat border zeroing
  prep0<<<5812, 256, 0, stream>>>(offin, w_off, w_dcn, w_r1, w_r2,
                                  offs_t, concat_t, wOffB, wDcnB, wR1B, wR2B);

  // K1 fused: offset conv (cout-split x3) + prep_prev overlapping slices.
  k1_fused<<<dim3(3, 384, 7), 256, 0, stream>>>(
      offs_t, wOffB, b_off, offf, prev, concat_t, gp);

  // K2: deformable conv -> concat_t channels [0,64).
  deform_mfma<<<1152, 256, 0, stream>>>(gp, offf, wDcnB, b_dcn, concat_t);

  // K3: r1 = leaky(conv(concat)) + r1_t border re-zero slice.
  conv_k3<<<dim3(3, 384, 2), 256, 0, stream>>>(concat_t, wR1B, b_r1, r1_t);

  // K4: out = aligned + leaky(conv(r1)).
  conv_k4<<<dim3(3, 384, 1), 256, 0, stream>>>(r1_t, wR2B, b_r2, concat_t, out);
}

// Round 17
// 137.481 us; speedup vs baseline: 1.1400x; 1.0049x over previous
//
#include <hip/hip_runtime.h>
#include <hip/hip_bf16.h>
#include <cstdint>
#include <cstddef>

constexpr int B_ = 2;
constexpr int HH = 192, WW = 192, HW_ = HH * WW;
constexpr int HP = 194, WPAD = 200;   // padded dims

typedef short bf16x8 __attribute__((ext_vector_type(8)));
typedef short s16x4  __attribute__((ext_vector_type(4)));
typedef float f32x4  __attribute__((ext_vector_type(4)));
typedef unsigned int u32x4 __attribute__((ext_vector_type(4)));

typedef __attribute__((address_space(1))) const void GLB;
typedef __attribute__((address_space(3))) void LDS;

__device__ __forceinline__ float bf2f(unsigned short h) {
  union { unsigned u; float f; } v; v.u = (unsigned)h << 16; return v.f;
}
__device__ __forceinline__ unsigned short f2bf(float f) {
  union { float f; unsigned u; } v; v.f = f;
  unsigned u = v.u;
  u += 0x7fffu + ((u >> 16) & 1u);
  return (unsigned short)(u >> 16);
}
__device__ __forceinline__ float leaky(float v) { return fmaxf(v, 0.1f * v); }

// ---------------------------------------------------------------------------
// prep0: fused (a) offsets NCHW->NHWC, (b) weight transforms, (c) border zero
// of offs_t + concat_t (r1_t borders are re-zeroed in K3 — gp clobbers them).
// ---------------------------------------------------------------------------
__global__ __launch_bounds__(256) void prep0(
    const float* __restrict__ offin,
    const float* __restrict__ w_off, const float* __restrict__ w_dcn,
    const float* __restrict__ w_r1,  const float* __restrict__ w_r2,
    unsigned short* __restrict__ offs_t, unsigned short* __restrict__ concat_t,
    unsigned short* __restrict__ wOffB, unsigned short* __restrict__ wDcnB,
    unsigned short* __restrict__ wR1B,  unsigned short* __restrict__ wR2B)
{
  __shared__ float tile[16][65];
  int bid = blockIdx.x;
  int t = threadIdx.x;

  if (bid < 4608) {
    int bx = bid % 12, by = bid / 12;
    int xc = bx * 16;
    int y = by % HH, b = by / HH;
    #pragma unroll
    for (int cp = 0; cp < 4; ++cp) {
      int c = cp * 16 + (t >> 4);
      tile[t & 15][c] = offin[((size_t)(b * 64 + c) * HH + y) * WW + xc + (t & 15)];
    }
    __syncthreads();
    int x = t >> 4, c4 = (t & 15) * 4;
    s16x4 s;
    #pragma unroll
    for (int j = 0; j < 4; ++j) s[j] = (short)f2bf(tile[x][c4 + j]);
    *(s16x4*)&offs_t[((size_t)(b * HP + y + 1) * WPAD + xc + x + 1) * 64 + c4] = s;
  } else if (bid < 5508) {
    int tid = (bid - 4608) * 256 + t;           // [0, 230400)
    const float* src; unsigned short* dst; int CI, CO, idx; bool dosw = true;
    if (tid < 82944)       { src = w_off; dst = wOffB; CI = 64;  CO = 144; idx = tid; }
    else if (tid < 119808) { src = w_dcn; dst = wDcnB; CI = 64;  CO = 64;  idx = tid - 82944; dosw = false; }
    else if (tid < 193536) { src = w_r1;  dst = wR1B;  CI = 128; CO = 64;  idx = tid - 119808; }
    else                   { src = w_r2;  dst = wR2B;  CI = 64;  CO = 64;  idx = tid - 193536; }
    int ci = idx % CI;
    int k  = (idx / CI) % 9;
    int o  = idx / (CI * 9);
    int pci = dosw ? (((((ci >> 3) ^ (o & 7))) << 3) | (ci & 7)) : ci;
    dst[((size_t)k * CO + o) * CI + pci] = f2bf(src[((size_t)o * CI + ci) * 9 + k]);
  } else {
    int tid = (bid - 5508) * 256 + t;           // covers 77600
    if (tid >= B_ * HP * WPAD) return;
    int x = tid % WPAD, y = (tid / WPAD) % HP, b = tid / (HP * WPAD);
    bool border = (y == 0) || (y >= 193) || (x == 0) || (x >= 193);
    if (!border) return;
    size_t px = (size_t)(b * HP + y) * WPAD + x;
    u32x4 z4 = {0u, 0u, 0u, 0u};
    u32x4* p0 = (u32x4*)(offs_t   + px * 64);
    u32x4* p1 = (u32x4*)(concat_t + px * 128);
    #pragma unroll
    for (int i = 0; i < 8; ++i)  p0[i] = z4;
    #pragma unroll
    for (int i = 0; i < 16; ++i) p1[i] = z4;
  }
}

// ---------------------------------------------------------------------------
// prep_prev body: prev NCHW f32 -> concat_t ch[64,128) + group-planar gp.
// ---------------------------------------------------------------------------
__device__ __forceinline__ void prep_prev_body(
    const float* __restrict__ src, unsigned short* __restrict__ concatT,
    unsigned short* __restrict__ gp, int bx, int by, float (*tile)[65], int t)
{
  int xc = bx * 16;
  int y = by % HH, b = by / HH;
  #pragma unroll
  for (int cp = 0; cp < 4; ++cp) {
    int c = cp * 16 + (t >> 4);
    tile[t & 15][c] = src[((size_t)(b * 64 + c) * HH + y) * WW + xc + (t & 15)];
  }
  __syncthreads();
  int x = t >> 4, c4 = (t & 15) * 4;
  s16x4 s;
  #pragma unroll
  for (int j = 0; j < 4; ++j) s[j] = (short)f2bf(tile[x][c4 + j]);
  *(s16x4*)&concatT[((size_t)(b * HP + y + 1) * WPAD + xc + x + 1) * 128 + 64 + c4] = s;
  int g = c4 >> 3, co = c4 & 7;
  *(s16x4*)&gp[((size_t)(b * 8 + g) * HW_ + (size_t)y * WW + xc + x) * 8 + co] = s;
}

// ---------------------------------------------------------------------------
// MFMA implicit-GEMM 3x3 conv body (shared by K1/K3/K4 kernels).
// ---------------------------------------------------------------------------
template<int CIN, int COUT, int NF, bool LEAKY_, int OUTMODE, bool DBUF, bool REGPF>
__device__ __forceinline__ void conv_body(
    const unsigned short* __restrict__ inT,
    const unsigned short* __restrict__ wS,
    const float* __restrict__ bias,
    const unsigned short* __restrict__ resid,
    void* __restrict__ outp,
    unsigned short* tile, unsigned short* wlds, int co0)
{
  constexpr int CPP  = CIN / 8;
  constexpr int TPX  = 72;
  constexpr int NCH  = TPX * CPP;
  constexpr int RPR  = NCH / 64;
  constexpr int NREG = 3 * RPR;
  constexpr int WSZ  = NF * 16 * CIN;
  constexpr int WCH  = WSZ / 8;
  static_assert(WCH % 128 == 0, "staging must use full waves");
  static_assert(!REGPF || (WCH % 256 == 0), "REGPF needs whole chunks/thread");
  constexpr int RPT  = WCH / 256;

  const int t = threadIdx.x;
  const int l = t & 63, wv = t >> 6;
  const int lr = l & 15, lq = l >> 4, lk = lq * 8;

  constexpr int NWG = 3 * 384;
  int lin = blockIdx.x + 3 * blockIdx.y;
  int swz = (lin & 7) * (NWG / 8) + (lin >> 3);
  int xq = swz % 3, yy = swz / 3;
  int y = yy % HH, b = yy / HH;
  int x0 = xq * 64;

  {
    const unsigned short* base = inT + ((size_t)(b * HP + y) * WPAD + x0) * CIN;
    for (int r = wv; r < NREG; r += 4) {
      int row = r / RPR;
      int rr  = r % RPR;
      int d   = rr * 64 + l;
      int p   = d / CPP;
      int cj  = d % CPP;
      int sc  = p * CPP + (cj ^ (p & (CPP - 1)));
      const unsigned short* src = base + (size_t)row * WPAD * CIN + (size_t)sc * 8;
      unsigned short* dst = &tile[(size_t)(row * NCH + rr * 64) * 8];
      __builtin_amdgcn_global_load_lds((GLB*)src, (LDS*)dst, 16, 0, 0);
    }
  }
  {
    const unsigned short* srcb = wS + (size_t)co0 * CIN;
    for (int r = t; r < WCH; r += 256)
      __builtin_amdgcn_global_load_lds((GLB*)(srcb + (size_t)r * 8),
                                       (LDS*)(&wlds[(size_t)r * 8]), 16, 0, 0);
  }
  __syncthreads();

  f32x4 acc[NF];
  #pragma unroll
  for (int f = 0; f < NF; ++f) acc[f] = f32x4{0.f, 0.f, 0.f, 0.f};

  #pragma unroll
  for (int k = 0; k < 9; ++k) {
    const int ky = k / 3, kx = k % 3;
    if (DBUF && k < 8) {
      const unsigned short* srcb = wS + (size_t)(k + 1) * COUT * CIN + (size_t)co0 * CIN;
      unsigned short* db = &wlds[(size_t)((k + 1) & 1) * WSZ];
      for (int r = t; r < WCH; r += 256)
        __builtin_amdgcn_global_load_lds((GLB*)(srcb + (size_t)r * 8),
                                         (LDS*)(db + (size_t)r * 8), 16, 0, 0);
    }
    u32x4 wpre[REGPF ? RPT : 1];
    if (REGPF && k < 8) {
      const unsigned short* srcb = wS + (size_t)(k + 1) * COUT * CIN + (size_t)co0 * CIN;
      #pragma unroll
      for (int r = 0; r < RPT; ++r)
        wpre[r] = *(const u32x4*)(srcb + (size_t)(t + r * 256) * 8);
    }
    {
      const unsigned short* wb = &wlds[DBUF ? (size_t)(k & 1) * WSZ : 0];
      const int px = wv * 16 + lr + kx;
      #pragma unroll
      for (int c = 0; c < CIN; c += 32) {
        int cj = (c + lk) >> 3;
        bf16x8 pf = *(const bf16x8*)
            &tile[(size_t)(ky * NCH + px * CPP + (cj ^ (px & (CPP - 1)))) * 8];
        #pragma unroll
        for (int f = 0; f < NF; ++f) {
          int co = f * 16 + lr;
          bf16x8 wf = *(const bf16x8*)&wb[(size_t)co * CIN + ((cj ^ (co & 7)) << 3)];
          if (OUTMODE == 0)
            acc[f] = __builtin_amdgcn_mfma_f32_16x16x32_bf16(pf, wf, acc[f], 0, 0, 0);
          else
            acc[f] = __builtin_amdgcn_mfma_f32_16x16x32_bf16(wf, pf, acc[f], 0, 0, 0);
        }
      }
    }
    if (DBUF) {
      __syncthreads();
    } else if (REGPF) {
      if (k < 8) {
        __syncthreads();
        #pragma unroll
        for (int r = 0; r < RPT; ++r)
          *(u32x4*)&wlds[(size_t)(t + r * 256) * 8] = wpre[r];
        __syncthreads();
      }
    } else if (k < 8) {
      __syncthreads();
      const unsigned short* srcb = wS + (size_t)(k + 1) * COUT * CIN + (size_t)co0 * CIN;
      for (int r = t; r < WCH; r += 256)
        __builtin_amdgcn_global_load_lds((GLB*)(srcb + (size_t)r * 8),
                                         (LDS*)(&wlds[(size_t)r * 8]), 16, 0, 0);
      __syncthreads();
    }
  }

  if (OUTMODE == 0) {
    int xs = x0 + wv * 16 + lq * 4;
    #pragma unroll
    for (int f = 0; f < NF; ++f) {
      int coG = co0 + f * 16 + lr;
      float bv = bias[coG];
      s16x4 s;
      #pragma unroll
      for (int j = 0; j < 4; ++j) {
        float v = acc[f][j] + bv;
        if (LEAKY_) v = leaky(v);
        s[j] = (short)f2bf(v);
      }
      *(s16x4*)((unsigned short*)outp + ((size_t)(b * COUT + coG) * HH + y) * WW + xs) = s;
    }
  } else if (OUTMODE == 1) {
    int x = x0 + wv * 16 + lr;
    #pragma unroll
    for (int f = 0; f < NF; ++f) {
      int coG = co0 + f * 16 + lq * 4;
      f32x4 bv = *(const f32x4*)&bias[coG];
      s16x4 s;
      #pragma unroll
      for (int j = 0; j < 4; ++j) {
        float v = acc[f][j] + bv[j];
        if (LEAKY_) v = leaky(v);
        s[j] = (short)f2bf(v);
      }
      *(s16x4*)((unsigned short*)outp + ((size_t)(b * HP + y + 1) * WPAD + x + 1) * 64 + coG) = s;
    }
  } else {
    int x = x0 + wv * 16 + lr;
    const unsigned short* rbase = resid + ((size_t)(b * HP + y + 1) * WPAD + x + 1) * 128;
    float* ob = (float*)outp + (size_t)b * 64 * HW_ + (size_t)y * WW + x;
    #pragma unroll
    for (int f = 0; f < NF; ++f) {
      int cobG = co0 + f * 16 + lq * 4;
      f32x4 bv = *(const f32x4*)&bias[cobG];
      s16x4 rv = *(const s16x4*)&rbase[cobG];
      #pragma unroll
      for (int j = 0; j < 4; ++j) {
        float v = acc[f][j] + bv[j];
        if (LEAKY_) v = leaky(v);
        v += bf2f((unsigned short)rv[j]);
        ob[(size_t)(cobG + j) * HW_] = v;
      }
    }
  }
}

// ---------------------------------------------------------------------------
// K1 fused: z<3 = offset conv slices; z in [3,7) = prep_prev slices.
// ---------------------------------------------------------------------------
__global__ __launch_bounds__(256, 4) void k1_fused(
    const unsigned short* __restrict__ offs_t,
    const unsigned short* __restrict__ wOffB,
    const float* __restrict__ b_off,
    unsigned short* __restrict__ offf,
    const float* __restrict__ prev,
    unsigned short* __restrict__ concat_t,
    unsigned short* __restrict__ gp)
{
  __shared__ __align__(16) unsigned short tile[3 * 72 * 64];   // 27648 B
  __shared__ __align__(16) unsigned short wlds[2 * 3 * 16 * 64];
  int z = blockIdx.z;
  if (z < 3) {
    conv_body<64, 144, 3, false, 0, true, false>(
        offs_t, wOffB, b_off, nullptr, offf, tile, wlds, z * 48);
  } else {
    int pid = (z - 3) * 1152 + blockIdx.x + 3 * blockIdx.y;    // [0, 4608)
    prep_prev_body(prev, concat_t, gp, pid % 12, pid / 12,
                   (float(*)[65])tile, threadIdx.x);
  }
}

// ---------------------------------------------------------------------------
// K3: z==0 = conv (concat 128 -> 64, REGPF); z==1 = border-zero r1_t.
// ---------------------------------------------------------------------------
__global__ __launch_bounds__(256, 4) void conv_k3(
    const unsigned short* __restrict__ concat_t,
    const unsigned short* __restrict__ wR1B,
    const float* __restrict__ b_r1,
    unsigned short* __restrict__ r1_t)
{
  __shared__ __align__(16) unsigned short tile[3 * 72 * 128];  // 55296 B
  __shared__ __align__(16) unsigned short wlds[4 * 16 * 128];  // 16384 B
  if (blockIdx.z == 1) {
    int tid = (blockIdx.x + 3 * blockIdx.y) * 256 + threadIdx.x;
    if (tid >= B_ * HP * WPAD) return;
    int x = tid % WPAD, y = (tid / WPAD) % HP, b = tid / (HP * WPAD);
    bool border = (y == 0) || (y >= 193) || (x == 0) || (x >= 193);
    if (!border) return;
    u32x4 z4 = {0u, 0u, 0u, 0u};
    u32x4* p2 = (u32x4*)(r1_t + ((size_t)(b * HP + y) * WPAD + x) * 64);
    #pragma unroll
    for (int i = 0; i < 8; ++i) p2[i] = z4;
    return;
  }
  conv_body<128, 64, 4, true, 1, false, true>(
      concat_t, wR1B, b_r1, nullptr, r1_t, tile, wlds, 0);
}

// ---------------------------------------------------------------------------
// K4: out = aligned + leaky(conv(r1)), DBUF.
// ---------------------------------------------------------------------------
__global__ __launch_bounds__(256, 4) void conv_k4(
    const unsigned short* __restrict__ r1_t,
    const unsigned short* __restrict__ wR2B,
    const float* __restrict__ b_r2,
    const unsigned short* __restrict__ concat_t,
    float* __restrict__ out)
{
  __shared__ __align__(16) unsigned short tile[3 * 72 * 64];
  __shared__ __align__(16) unsigned short wlds[2 * 4 * 16 * 64];
  conv_body<64, 64, 4, true, 2, true, false>(
      r1_t, wR2B, b_r2, concat_t, out, tile, wlds, 0);
}

// ---------------------------------------------------------------------------
// Deformable conv, R17: 2-row x 16-col tile, 128-thread blocks (2 waves).
// Window 6 rows x 24 cols x 8 groups; group stride 145 slots (bank tilt,
// 145*16 = 2320 ≡ 16 mod 128B). Slot space padded to 1280 = 10*128 so every
// global_load_lds trip is a FULL wave (R10 lesson). Grid 2304 (9 blocks/CU,
// 8 resident by LDS) — tests the TLP/grid-granularity axis (never varied).
// ---------------------------------------------------------------------------
__global__ __launch_bounds__(128, 4) void deform_mfma(
    const unsigned short* __restrict__ gp,    // [b][8][192][192][8] bf16
    const unsigned short* __restrict__ off,   // [b][144][192][192] bf16
    const unsigned short* __restrict__ wD,    // [9][64][64] bf16 plain
    const float* __restrict__ bias,
    unsigned short* __restrict__ concatT)     // [b][HP][WPAD][128], writes ch0-63
{
  __shared__ __align__(16) unsigned short win[1280 * 8];   // 20480 B
  const int t = threadIdx.x;                  // 0..127
  const int l = t & 63, wv = t >> 6;          // wv 0..1 = row
  const int lr = l & 15, lq = l >> 4;

  int lin = blockIdx.x;                       // 2304 blocks, 2304 % 8 == 0
  int swz = (lin & 7) * 288 + (lin >> 3);     // XCD-aware bijective
  int xt = swz % 12;
  int rest = swz / 12;                        // 0..191
  int yp = rest % 96, b = rest / 96;
  int Y = yp * 2, x0 = xt * 16;
  int yrow = Y + wv;                          // this wave's output row
  int xpix = x0 + lr;                         // this lane's pixel

  const int wy = Y - 2, wx = x0 - 3;          // window origin: 6 rows x 24 cols
  const unsigned short* gpb = gp + (size_t)b * 8 * HW_ * 8;

  // ---- stage window: 1280 slots x 16B, 10 full-wave trips of 128 threads
  #pragma unroll
  for (int i = 0; i < 10; ++i) {
    int p  = t + i * 128;                     // 0..1279
    int g  = min(p / 145, 7);
    int rc = p - g * 145;
    int rcc = min(rc, 143);                   // pad slots -> clamped source
    int r  = rcc / 24;
    int c  = rcc - r * 24;
    int yr = min(max(wy + r, 0), HH - 1);
    int xc = min(max(wx + c, 0), WW - 1);
    const unsigned short* src = gpb + ((size_t)g * HW_ + (size_t)yr * WW + xc) * 8;
    __builtin_amdgcn_global_load_lds((GLB*)src,
                                     (LDS*)(win + (size_t)p * 8), 16, 0, 0);
  }

  // ---- preload offsets, packed (dy | dx<<16) per (group-pair, tap)
  unsigned dd[2][9];
  #pragma unroll
  for (int gi = 0; gi < 2; ++gi) {
    int g = lq + gi * 4;
    const unsigned short* op = off + ((size_t)(b * 144 + g * 18) * HH + yrow) * WW + xpix;
    #pragma unroll
    for (int k = 0; k < 9; ++k) {
      unsigned dyv = op[(size_t)(2 * k) * HW_];
      unsigned dxv = op[(size_t)(2 * k + 1) * HW_];
      dd[gi][k] = dyv | (dxv << 16);
    }
  }

  __syncthreads();                            // window ready (single barrier)

  f32x4 acc[4];
  #pragma unroll
  for (int f = 0; f < 4; ++f) acc[f] = f32x4{0.f, 0.f, 0.f, 0.f};

  #pragma unroll
  for (int k = 0; k < 9; ++k) {
    const int ky = k / 3, kx = k % 3;
    bf16x8 pf0, pf1;
    #pragma unroll
    for (int gi = 0; gi < 2; ++gi) {
      int g = lq + gi * 4;
      float dyv = bf2f((unsigned short)(dd[gi][k] & 0xffffu));
      float dxv = bf2f((unsigned short)(dd[gi][k] >> 16));
      float py = (float)(yrow - 1 + ky) + dyv;
      float px = (float)(xpix - 1 + kx) + dxv;
      float fy0 = floorf(py), fx0 = floorf(px);
      float wy1 = py - fy0, wx1 = px - fx0;
      float wy0 = 1.f - wy1, wx0 = 1.f - wx1;
      bool vy0 = (fy0 >= 0.f)  && (fy0 <= 191.f);
      bool vy1 = (fy0 >= -1.f) && (fy0 <= 190.f);
      bool vx0 = (fx0 >= 0.f)  && (fx0 <= 191.f);
      bool vx1 = (fx0 >= -1.f) && (fx0 <= 190.f);
      float c00 = (vy0 && vx0) ? wy0 * wx0 : 0.f;
      float c01 = (vy0 && vx1) ? wy0 * wx1 : 0.f;
      float c10 = (vy1 && vx0) ? wy1 * wx0 : 0.f;
      float c11 = (vy1 && vx1) ? wy1 * wx1 : 0.f;
      int iy0 = (int)fminf(fmaxf(fy0, 0.f), 191.f);
      int iy1 = (int)fminf(fmaxf(fy0 + 1.f, 0.f), 191.f);
      int ix0 = (int)fminf(fmaxf(fx0, 0.f), 191.f);
      int ix1 = (int)fminf(fmaxf(fx0 + 1.f, 0.f), 191.f);
      bool inw = (iy0 >= wy) && (iy1 <= wy + 5) && (ix0 >= wx) && (ix1 <= wx + 23);
      int ry0 = min(max(iy0 - wy, 0), 5), ry1 = min(max(iy1 - wy, 0), 5);
      int rx0 = min(max(ix0 - wx, 0), 23), rx1 = min(max(ix1 - wx, 0), 23);
      const unsigned short* wg = win + (size_t)g * (145 * 8);
      bf16x8 v00 = *(const bf16x8*)(wg + ((size_t)ry0 * 24 + rx0) * 8);
      bf16x8 v01 = *(const bf16x8*)(wg + ((size_t)ry0 * 24 + rx1) * 8);
      bf16x8 v10 = *(const bf16x8*)(wg + ((size_t)ry1 * 24 + rx0) * 8);
      bf16x8 v11 = *(const bf16x8*)(wg + ((size_t)ry1 * 24 + rx1) * 8);
      if (!__all((int)inw)) {                 // rare: exact global fallback
        if (!inw) {
          const unsigned short* bb = gpb + (size_t)g * HW_ * 8;
          v00 = *(const bf16x8*)(bb + ((size_t)iy0 * WW + ix0) * 8);
          v01 = *(const bf16x8*)(bb + ((size_t)iy0 * WW + ix1) * 8);
          v10 = *(const bf16x8*)(bb + ((size_t)iy1 * WW + ix0) * 8);
          v11 = *(const bf16x8*)(bb + ((size_t)iy1 * WW + ix1) * 8);
        }
      }
      bf16x8 sv;
      #pragma unroll
      for (int j = 0; j < 8; ++j) {
        float s = bf2f((unsigned short)v00[j]) * c00
                + bf2f((unsigned short)v01[j]) * c01
                + bf2f((unsigned short)v10[j]) * c10
                + bf2f((unsigned short)v11[j]) * c11;
        sv[j] = (short)f2bf(s);
      }
      if (gi == 0) pf0 = sv; else pf1 = sv;
    }
    #pragma unroll
    for (int f = 0; f < 4; ++f) {
      bf16x8 wf = *(const bf16x8*)&wD[((size_t)k * 64 + f * 16 + lr) * 64 + lq * 8];
      acc[f] = __builtin_amdgcn_mfma_f32_16x16x32_bf16(wf, pf0, acc[f], 0, 0, 0);
    }
    #pragma unroll
    for (int f = 0; f < 4; ++f) {
      bf16x8 wf = *(const bf16x8*)&wD[((size_t)k * 64 + f * 16 + lr) * 64 + 32 + lq * 8];
      acc[f] = __builtin_amdgcn_mfma_f32_16x16x32_bf16(wf, pf1, acc[f], 0, 0, 0);
    }
  }

  // epilogue: NHWC bf16 into concat channels [0,64)
  unsigned short* outc = concatT + (size_t)b * HP * WPAD * 128;
  #pragma unroll
  for (int f = 0; f < 4; ++f) {
    int co = f * 16 + lq * 4;
    f32x4 bv = *(const f32x4*)&bias[co];
    s16x4 s;
    #pragma unroll
    for (int j = 0; j < 4; ++j) s[j] = (short)f2bf(acc[f][j] + bv[j]);
    *(s16x4*)&outc[((size_t)(yrow + 1) * WPAD + xpix + 1) * 128 + co] = s;
  }
}

// ---------------------------------------------------------------------------
extern "C" void kernel_launch(void* const* d_in, const int* in_sizes, int n_in,
                              void* d_out, int out_size, void* d_ws, size_t ws_size,
                              hipStream_t stream)
{
  const float* prev  = (const float*)d_in[0];
  const float* offin = (const float*)d_in[1];
  const float* w_off = (const float*)d_in[2];
  const float* b_off = (const float*)d_in[3];
  const float* w_dcn = (const float*)d_in[4];
  const float* b_dcn = (const float*)d_in[5];
  const float* w_r1  = (const float*)d_in[6];
  const float* b_r1  = (const float*)d_in[7];
  const float* w_r2  = (const float*)d_in[8];
  const float* b_r2  = (const float*)d_in[9];
  float* out = (float*)d_out;

  char* p = (char*)d_ws;
  unsigned short* offs_t   = (unsigned short*)p; p += (size_t)B_ * HP * WPAD * 64 * 2;   //  9.93 MB
  unsigned short* concat_t = (unsigned short*)p; p += (size_t)B_ * HP * WPAD * 128 * 2;  // 19.87 MB
  unsigned short* r1_t     = (unsigned short*)p; p += (size_t)B_ * HP * WPAD * 64 * 2;   //  9.93 MB
  unsigned short* offf     = (unsigned short*)p; p += (size_t)B_ * 144 * HW_ * 2;        // 21.23 MB
  unsigned short* wOffB    = (unsigned short*)p; p += 144 * 576 * 2;
  unsigned short* wDcnB    = (unsigned short*)p; p += 64 * 576 * 2;
  unsigned short* wR1B     = (unsigned short*)p; p += 64 * 1152 * 2;
  unsigned short* wR2B     = (unsigned short*)p; p += 64 * 576 * 2;                      // total ~61.4 MB
  // gp (9.44 MB) aliases r1_t (9.93 MB): written by k1_fused's prep slices,
  // read by K2, then overwritten by K3 (whose z=1 slice re-zeros the borders).
  unsigned short* gp = r1_t;

  // prep0: offsets->NHWC + weight transforms + offs/concat border zeroing
  prep0<<<5812, 256, 0, stream>>>(offin, w_off, w_dcn, w_r1, w_r2,
                                  offs_t, concat_t, wOffB, wDcnB, wR1B, wR2B);

  // K1 fused: offset conv (cout-split x3) + prep_prev overlapping slices.
  k1_fused<<<dim3(3, 384, 7), 256, 0, stream>>>(
      offs_t, wOffB, b_off, offf, prev, concat_t, gp);

  // K2: deformable conv -> concat_t channels [0,64). 2x16 tile, grid 2304.
  deform_mfma<<<2304, 128, 0, stream>>>(gp, offf, wDcnB, b_dcn, concat_t);

  // K3: r1 = leaky(conv(concat)) + r1_t border re-zero slice.
  conv_k3<<<dim3(3, 384, 2), 256, 0, stream>>>(concat_t, wR1B, b_r1, r1_t);

  // K4: out = aligned + leaky(conv(r1)).
  conv_k4<<<dim3(3, 384, 1), 256, 0, stream>>>(r1_t, wR2B, b_r2, concat_t, out);
}